// Round 1
// 766.263 us; speedup vs baseline: 1.0017x; 1.0017x over previous
//
#include <hip/hip_runtime.h>

// RelativeBPEWORDFusionMultiheadAttention on MI355X (gfx950). FP32 in/out.
// Factorization: fused = (MQ)(MK)^T + M·Rel·M^T (content Dekker-bf16, Rel fp16).
// Round 10: band+prefix decomposition of M·Rel. Rel[s][w] is separable outside
// a 31-wide band (clip makes it R[w][32] / R[w][0]), so C1 = K=64 windowed MFMA
// + two coarse (16-granular) prefix scalars per (q, s-tile). Replaces the dense
// K=512 stage1 GEMM (8x less MFMA work) and shrinks RelT 8x. Also: logits block
// x/y swap so each C1r q-panel's k-sweep stays on one XCD L2.

#define DEV __device__ __forceinline__
#define GAS(x) ((const __attribute__((address_space(1))) unsigned*)(x))
#define LAS(x) ((__attribute__((address_space(3))) unsigned*)(x))

typedef unsigned short u16;
typedef __attribute__((ext_vector_type(8))) short short8;
typedef __attribute__((ext_vector_type(8))) _Float16 half8;
typedef __attribute__((ext_vector_type(4))) float floatx4;

DEV float bf2f(u16 u) { union { unsigned u; float f; } v; v.u = ((unsigned)u) << 16; return v.f; }
DEV u16 f2bf(float f) {
  union { float f; unsigned u; } v; v.f = f;
  unsigned r = v.u + 0x7FFFu + ((v.u >> 16) & 1u);  // RNE
  return (u16)(r >> 16);
}
DEV u16 f2h_bits(float f) { union { _Float16 h; u16 u; } v; v.h = (_Float16)f; return v.u; }

// ---- LDS tile [128][32] u16, 16B-chunk XOR swizzle (source-side permute) ----
DEV void stage_u16(const u16* g, int ld, u16* lds, int tid) {
#pragma unroll
  for (int p = 0; p < 2; ++p) {
    int o = (p * 256 + tid) * 16;
    int r = o >> 6, c = (o >> 4) & 3, sc = c ^ ((r >> 1) & 3);
    __builtin_amdgcn_global_load_lds(GAS(g + (size_t)r * ld + sc * 8),
                                     LAS((char*)lds + o), 16, 0, 0);
  }
}

DEV void stage_u16_half(const u16* g, int ld, u16* lds, int tid, int p) {
  int o = (p * 256 + tid) * 16;
  int r = o >> 6, c = (o >> 4) & 3, sc = c ^ ((r >> 1) & 3);
  __builtin_amdgcn_global_load_lds(GAS(g + (size_t)(r - p * 64) * ld + sc * 8),
                                   LAS((char*)lds + o), 16, 0, 0);
}

DEV void stage_f32_bf(const float* g, int ld, u16* lds, int tid) {
#pragma unroll
  for (int p = 0; p < 2; ++p) {
    int o = (p * 256 + tid) * 16;
    int r = o >> 6, c = (o >> 4) & 3, sc = c ^ ((r >> 1) & 3);
    const float* src = g + (size_t)r * ld + sc * 8;
    union { short8 s; u16 u[8]; } oh;
#pragma unroll
    for (int j = 0; j < 8; ++j) oh.u[j] = f2bf(src[j]);
    *(short8*)((char*)lds + o) = oh.s;
  }
}

DEV void stage_f32_split(const float* g, int ld, u16* ldsh, u16* ldsl, int tid) {
#pragma unroll
  for (int p = 0; p < 2; ++p) {
    int o = (p * 256 + tid) * 16;
    int r = o >> 6, c = (o >> 4) & 3, sc = c ^ ((r >> 1) & 3);
    const float* src = g + (size_t)r * ld + sc * 8;
    union { short8 s; u16 u[8]; } oh, ol;
#pragma unroll
    for (int j = 0; j < 8; ++j) {
      float f = src[j];
      u16 h = f2bf(f);
      oh.u[j] = h;
      ol.u[j] = f2bf(f - bf2f(h));
    }
    *(short8*)((char*)ldsh + o) = oh.s;
    *(short8*)((char*)ldsl + o) = ol.s;
  }
}

DEV short8 frag_ld(const u16* lds, int row, int quad) {
  int c = quad ^ ((row >> 1) & 3);
  return *(const short8*)(lds + row * 32 + c * 8);
}

DEV void mma_bf16(const u16* As, const u16* Bs, int wr, int wc, int m, int quad, floatx4 acc[4][4]) {
  short8 af[4], bf[4];
#pragma unroll
  for (int t = 0; t < 4; ++t) af[t] = frag_ld(As, wr * 64 + t * 16 + m, quad);
#pragma unroll
  for (int t = 0; t < 4; ++t) bf[t] = frag_ld(Bs, wc * 64 + t * 16 + m, quad);
#pragma unroll
  for (int rt = 0; rt < 4; ++rt)
#pragma unroll
    for (int ct = 0; ct < 4; ++ct)
      acc[rt][ct] = __builtin_amdgcn_mfma_f32_16x16x32_bf16(af[rt], bf[ct], acc[rt][ct], 0, 0, 0);
}

DEV void mma_f16(const u16* As, const u16* Bs, int wr, int wc, int m, int quad, floatx4 acc[4][4]) {
  union { short8 s; half8 h; } af[4], bf[4];
#pragma unroll
  for (int t = 0; t < 4; ++t) af[t].s = frag_ld(As, wr * 64 + t * 16 + m, quad);
#pragma unroll
  for (int t = 0; t < 4; ++t) bf[t].s = frag_ld(Bs, wc * 64 + t * 16 + m, quad);
#pragma unroll
  for (int rt = 0; rt < 4; ++rt)
#pragma unroll
    for (int ct = 0; ct < 4; ++ct)
      acc[rt][ct] = __builtin_amdgcn_mfma_f32_16x16x32_f16(af[rt].h, bf[ct].h, acc[rt][ct], 0, 0, 0);
}

// Dekker 3-pass: hh + hl + lh (bf16 operands, ~2^-16 effective)
DEV void mma_split(const u16* AsH, const u16* AsL, const u16* BsH, const u16* BsL,
                   int wr, int wc, int m, int quad, floatx4 acc[4][4]) {
  short8 ah[4], al[4], bh[4], bl[4];
#pragma unroll
  for (int t = 0; t < 4; ++t) {
    ah[t] = frag_ld(AsH, wr * 64 + t * 16 + m, quad);
    al[t] = frag_ld(AsL, wr * 64 + t * 16 + m, quad);
    bh[t] = frag_ld(BsH, wc * 64 + t * 16 + m, quad);
    bl[t] = frag_ld(BsL, wc * 64 + t * 16 + m, quad);
  }
#pragma unroll
  for (int rt = 0; rt < 4; ++rt)
#pragma unroll
    for (int ct = 0; ct < 4; ++ct) {
      acc[rt][ct] = __builtin_amdgcn_mfma_f32_16x16x32_bf16(ah[rt], bh[ct], acc[rt][ct], 0, 0, 0);
      acc[rt][ct] = __builtin_amdgcn_mfma_f32_16x16x32_bf16(ah[rt], bl[ct], acc[rt][ct], 0, 0, 0);
      acc[rt][ct] = __builtin_amdgcn_mfma_f32_16x16x32_bf16(al[rt], bh[ct], acc[rt][ct], 0, 0, 0);
    }
}

DEV void acc_zero(floatx4 acc[4][4]) {
  floatx4 z = {0.f, 0.f, 0.f, 0.f};
#pragma unroll
  for (int i = 0; i < 4; ++i)
#pragma unroll
    for (int j = 0; j < 4; ++j) acc[i][j] = z;
}

// ---------------- input pre-conversion ----------------
struct CvtB { const float* src[5]; u16* dst[5]; int n8[5]; };
__global__ __launch_bounds__(256) void cvt_bf_kernel(CvtB a) {
  int z = blockIdx.z;
  int i = blockIdx.x * 256 + threadIdx.x;
  if (i >= a.n8[z]) return;
  const float* s = a.src[z] + (size_t)i * 8;
  union { short8 v; u16 u[8]; } o;
#pragma unroll
  for (int j = 0; j < 8; ++j) o.u[j] = f2bf(s[j]);
  *(short8*)(a.dst[z] + (size_t)i * 8) = o.v;
}

struct CvtS { const float* src[3]; u16* dh[3]; u16* dl[3]; int n8[3]; };
__global__ __launch_bounds__(256) void cvt_split_kernel(CvtS a) {
  int z = blockIdx.z;
  int i = blockIdx.x * 256 + threadIdx.x;
  if (i >= a.n8[z]) return;
  const float* s = a.src[z] + (size_t)i * 8;
  union { short8 v; u16 u[8]; } oh, ol;
#pragma unroll
  for (int j = 0; j < 8; ++j) {
    float f = s[j];
    u16 h = f2bf(f);
    oh.u[j] = h;
    ol.u[j] = f2bf(f - bf2f(h));
  }
  *(short8*)(a.dh[z] + (size_t)i * 8) = oh.v;
  *(short8*)(a.dl[z] + (size_t)i * 8) = ol.v;
}

// ---------------- all 5 projections, one launch ----------------
// z: 0=q_bpe(bf16) 1=k_bpe(bf16) 2=V->VT(bf16) 3=q_word(Dekker->transposed h/l)
//    4=k_word(Dekker->transposed h/l)
struct PAll {
  const float* Xf[5]; const float* Wf[5];
  const u16* Xh[5]; const u16* Xl[5]; const u16* Wh[5]; const u16* Wl[5];
  const float* bias[5]; float scale[5];
  u16* dh[5]; u16* dl[5]; int T[5]; int md[5]; int prep;
};

__global__ __launch_bounds__(256) void proj_all_kernel(PAll a) {
  const int z = blockIdx.z;
  const int T = a.T[z];
  if ((int)blockIdx.y >= (T >> 5)) return;
  __shared__ __align__(16) u16 AsH[4096], AsL[4096], BsH[4096], BsL[4096];
  const int tid = threadIdx.x;
  const int lane = tid & 63, wv = tid >> 6, wr = wv >> 1, wc = wv & 1;
  const int m = lane & 15, quad = lane >> 4;
  const int md = a.md[z], prep = a.prep;
  const size_t arow = (size_t)blockIdx.y * 128 * 1024;
  const size_t brow = (size_t)blockIdx.x * 128 * 1024;
  floatx4 acc[4][4];
  acc_zero(acc);
  for (int k0 = 0; k0 < 1024; k0 += 32) {
    __syncthreads();
    if (md == 2) {
      if (prep) {
        stage_u16(a.Xh[z] + arow + k0, 1024, AsH, tid);
        stage_u16(a.Xl[z] + arow + k0, 1024, AsL, tid);
        stage_u16(a.Wh[z] + brow + k0, 1024, BsH, tid);
        stage_u16(a.Wl[z] + brow + k0, 1024, BsL, tid);
      } else {
        stage_f32_split(a.Xf[z] + arow + k0, 1024, AsH, AsL, tid);
        stage_f32_split(a.Wf[z] + brow + k0, 1024, BsH, BsL, tid);
      }
    } else {
      if (prep) {
        stage_u16(a.Xh[z] + arow + k0, 1024, AsH, tid);
        stage_u16(a.Wh[z] + brow + k0, 1024, BsH, tid);
      } else {
        stage_f32_bf(a.Xf[z] + arow + k0, 1024, AsH, tid);
        stage_f32_bf(a.Wf[z] + brow + k0, 1024, BsH, tid);
      }
    }
    __syncthreads();
    if (md == 2) mma_split(AsH, AsL, BsH, BsL, wr, wc, m, quad, acc);
    else         mma_bf16(AsH, BsH, wr, wc, m, quad, acc);
  }
  const float scale = a.scale[z];
  const float* bias = a.bias[z];
  u16* dh = a.dh[z];
  u16* dl = a.dl[z];
  const int row0 = blockIdx.y * 128 + wr * 64 + quad * 4;
  const int col0 = blockIdx.x * 128 + wc * 64 + m;
#pragma unroll
  for (int rt = 0; rt < 4; ++rt)
#pragma unroll
    for (int ct = 0; ct < 4; ++ct) {
      int col = col0 + ct * 16;
      float bi = bias[col];
      int h = col >> 6, d = col & 63;
#pragma unroll
      for (int rg = 0; rg < 4; ++rg) {
        int row = row0 + rt * 16 + rg;
        int t = row >> 2, bb = row & 3, n = bb * 16 + h;
        float val = (acc[rt][ct][rg] + bi) * scale;
        if (md == 1) {
          dh[((size_t)n * 64 + d) * 1024 + t] = f2bf(val);        // VT[n][d][t]
        } else if (md == 2) {
          size_t idx = ((size_t)n * 64 + d) * 512 + t;            // [n][d][w] transposed
          u16 hh = f2bf(val);
          dh[idx] = hh;
          dl[idx] = f2bf(val - bf2f(hh));
        } else {
          dh[((size_t)n * T + t) * 64 + d] = f2bf(val);           // [n][t][d]
        }
      }
    }
}

// ---------------- M -> Mh,Ml (bf16 Dekker) + Mf (fp16) ----------------
__global__ __launch_bounds__(256) void msplit_kernel(const float* __restrict__ M,
                                                     u16* __restrict__ Mh, u16* __restrict__ Ml,
                                                     u16* __restrict__ Mf) {
  int i = blockIdx.x * 256 + threadIdx.x;
  float f = M[i];
  u16 h = f2bf(f);
  Mh[i] = h;
  Ml[i] = f2bf(f - bf2f(h));
  Mf[i] = f2h_bits(f);
}

// ---------------- rel tables ----------------
__global__ __launch_bounds__(256) void rel_bpe_kernel(const u16* __restrict__ q,
                                                      const float* __restrict__ relk,
                                                      float* __restrict__ R) {
  int nt = blockIdx.x * 256 + threadIdx.x;
  float qv[64];
#pragma unroll
  for (int c = 0; c < 8; ++c) {
    union { short8 s; u16 u[8]; } uh; uh.s = *(const short8*)(q + (size_t)nt * 64 + c * 8);
#pragma unroll
    for (int j = 0; j < 8; ++j) qv[c * 8 + j] = bf2f(uh.u[j]);
  }
  for (int r = 0; r < 33; ++r) {
    const float* krow = relk + r * 64;
    float s = 0.f;
#pragma unroll
    for (int d = 0; d < 64; ++d) s += qv[d] * krow[d];
    R[(size_t)nt * 33 + r] = s;
  }
}

__global__ __launch_bounds__(256) void rel_word_kernel(const u16* __restrict__ qh, const u16* __restrict__ ql,
                                                       const float* __restrict__ relk,
                                                       float* __restrict__ R) {
  int nt = blockIdx.x * 256 + threadIdx.x;
  int n = nt >> 9, w = nt & 511;
  float qv[64];
#pragma unroll
  for (int d = 0; d < 64; ++d) {
    size_t idx = ((size_t)n * 64 + d) * 512 + w;
    qv[d] = bf2f(qh[idx]) + bf2f(ql[idx]);
  }
  for (int r = 0; r < 33; ++r) {
    const float* krow = relk + r * 64;
    float s = 0.f;
#pragma unroll
    for (int d = 0; d < 64; ++d) s += qv[d] * krow[d];
    R[(size_t)nt * 33 + r] = s;
  }
}

// ---- RelT_win build: 64-wide windowed Rel tiles, fp16 -----------------------
// RelT[nl][t][s_local][w_local] = R[n][w0+w_local][clip((32t+s_local)-(w0+w_local))+16]
// w0(t) = clamp(32t-16, 0, 448). Exact clipped values inside the window; the
// clipped mass outside the window is handled by coarse prefix scalars (below).
__global__ __launch_bounds__(256) void relmat64_kernel(const float* __restrict__ Rw,
                                                       u16* __restrict__ RT, int n0) {
  int i = blockIdx.x * 256 + threadIdx.x;            // NC*16*32*8 short8 items
  int w8 = i & 7, s = (i >> 3) & 31, t = (i >> 8) & 15, nl = i >> 12;
  int n = n0 + nl;
  int w0 = (t == 0) ? 0 : (t == 15 ? 448 : 32 * t - 16);
  int sg = t * 32 + s;
  const float* R = Rw + (size_t)n * 512 * 33;
  union { short8 v; u16 u[8]; } o;
#pragma unroll
  for (int j = 0; j < 8; ++j) {
    int w = w0 + w8 * 8 + j;
    int d = sg - w; d = d < -16 ? -16 : (d > 16 ? 16 : d);
    o.u[j] = f2h_bits(R[(size_t)w * 33 + d + 16]);
  }
  *(short8*)(RT + (size_t)i * 8) = o.v;
}

// ---- coarse prefixes: PS[nl][q][0..32]=sum_{w<16i} Mf*R[w][32]  (PreA)
//                       PS[nl][q][33+i] =sum_{w>=16i} Mf*R[w][0]  (SufB)
__global__ __launch_bounds__(256) void prefix16_kernel(const u16* __restrict__ Mf,
                                                       const float* __restrict__ Rw,
                                                       float* __restrict__ PS, int n0) {
  const int nl = blockIdx.y, n = n0 + nl, b = n >> 4;
  const int q = blockIdx.x * 256 + threadIdx.x;
  const u16* mrow = Mf + ((size_t)b * 1024 + q) * 512;
  const float* R = Rw + (size_t)n * 512 * 33;
  float* ps = PS + ((size_t)nl * 1024 + q) * 66;
  float blkA[32], blkB[32];
#pragma unroll
  for (int t = 0; t < 32; ++t) {
    float a = 0.f, bb = 0.f;
#pragma unroll
    for (int c = 0; c < 2; ++c) {
      union { short8 s; _Float16 h[8]; } u;
      u.s = *(const short8*)(mrow + t * 16 + c * 8);
#pragma unroll
      for (int j = 0; j < 8; ++j) {
        int w = t * 16 + c * 8 + j;
        float mv = (float)u.h[j];
        a += mv * R[(size_t)w * 33 + 32];
        bb += mv * R[(size_t)w * 33];
      }
    }
    blkA[t] = a; blkB[t] = bb;
  }
  float run = 0.f;
#pragma unroll
  for (int i = 0; i < 33; ++i) { ps[i] = run; if (i < 32) run += blkA[i]; }
  float tot = 0.f;
#pragma unroll
  for (int i = 0; i < 32; ++i) tot += blkB[i];
  run = tot;
#pragma unroll
  for (int i = 0; i < 33; ++i) { ps[33 + i] = run; if (i < 32) run -= blkB[i]; }
}

// ---- stage1 band: C1r[nl][q][s] = K=64 windowed MFMA + alpha[q] + beta[q] ----
// block: 128 q x 32 s (one s-tile), 2 K-steps. alpha = PreA[w0/16],
// beta = SufB[(w0+64)/16]; both exact because |s-w| >= 17 outside the window.
__global__ __launch_bounds__(256) void stage1band_kernel(const u16* __restrict__ Mf,
                                                         const u16* __restrict__ RT,
                                                         const float* __restrict__ PS,
                                                         u16* __restrict__ C1r, int n0) {
  __shared__ __align__(16) u16 As[4096], Bs[1024];
  const int tid = threadIdx.x, t = blockIdx.x, nl = blockIdx.z, n = n0 + nl, b = n >> 4;
  const int lane = tid & 63, wv = tid >> 6;
  const int m = lane & 15, quad = lane >> 4;
  const int w0 = (t == 0) ? 0 : (t == 15 ? 448 : 32 * t - 16);
  const size_t ma = ((size_t)b * 1024 + blockIdx.y * 128) * 512 + w0;
  const u16* rt = RT + ((size_t)nl * 16 + t) * 2048;
  floatx4 acc[2][2];
  floatx4 z = {0.f, 0.f, 0.f, 0.f};
  acc[0][0] = z; acc[0][1] = z; acc[1][0] = z; acc[1][1] = z;
#pragma unroll
  for (int k0 = 0; k0 < 64; k0 += 32) {
    __syncthreads();
    stage_u16(Mf + ma + k0, 512, As, tid);
    if (tid < 128) {
      int o = tid * 16;
      int r = o >> 6, c = (o >> 4) & 3, sc = c ^ ((r >> 1) & 3);
      __builtin_amdgcn_global_load_lds(GAS(rt + k0 + (size_t)r * 64 + sc * 8),
                                       LAS((char*)Bs + o), 16, 0, 0);
    }
    __syncthreads();
    union { short8 s; half8 h; } af[2], bf[2];
#pragma unroll
    for (int i = 0; i < 2; ++i) af[i].s = frag_ld(As, wv * 32 + i * 16 + m, quad);
#pragma unroll
    for (int i = 0; i < 2; ++i) bf[i].s = frag_ld(Bs, i * 16 + m, quad);
#pragma unroll
    for (int i = 0; i < 2; ++i)
#pragma unroll
      for (int j = 0; j < 2; ++j)
        acc[i][j] = __builtin_amdgcn_mfma_f32_16x16x32_f16(af[i].h, bf[j].h, acc[i][j], 0, 0, 0);
  }
  const int ia = w0 >> 4, ib = (w0 + 64) >> 4;
  const float* ps = PS + ((size_t)nl * 1024 + blockIdx.y * 128) * 66;
#pragma unroll
  for (int i = 0; i < 2; ++i)
#pragma unroll
    for (int rg = 0; rg < 4; ++rg) {
      int row = wv * 32 + i * 16 + quad * 4 + rg;
      float ab = ps[(size_t)row * 66 + ia] + ps[(size_t)row * 66 + 33 + ib];
      int q = blockIdx.y * 128 + row;
#pragma unroll
      for (int j = 0; j < 2; ++j) {
        int s = t * 32 + j * 16 + m;
        C1r[((size_t)nl * 1024 + q) * 512 + s] = f2h_bits(acc[i][j][rg] + ab);
      }
    }
}

// ---------------- MQ/MK: [1024,64] = M[1024,512] x {Q,K}^T, Dekker 3-pass ------
__global__ __launch_bounds__(256) void mqk_kernel(const u16* __restrict__ Mh, const u16* __restrict__ Ml,
                                                  const u16* __restrict__ qwTh, const u16* __restrict__ qwTl,
                                                  const u16* __restrict__ kwTh, const u16* __restrict__ kwTl,
                                                  float* __restrict__ MQ, float* __restrict__ MK, int n0) {
  __shared__ __align__(16) u16 AsH[4096], AsL[4096], BsH[4096], BsL[4096];
  const int tid = threadIdx.x, nl = blockIdx.y, n = n0 + nl, b = n >> 4;
  const int lane = tid & 63, wv = tid >> 6, wr = wv >> 1, wc = wv & 1;
  const int m = lane & 15, quad = lane >> 4;
  const size_t ma = ((size_t)b * 1024 + blockIdx.x * 128) * 512;
  const u16* Qh = qwTh + (size_t)n * 32768;
  const u16* Ql = qwTl + (size_t)n * 32768;
  const u16* Kh = kwTh + (size_t)n * 32768;
  const u16* Kl = kwTl + (size_t)n * 32768;
  floatx4 acc[4][4];
  acc_zero(acc);
  for (int k0 = 0; k0 < 512; k0 += 32) {
    __syncthreads();
    stage_u16(Mh + ma + k0, 512, AsH, tid);
    stage_u16(Ml + ma + k0, 512, AsL, tid);
    stage_u16_half(Qh + k0, 512, BsH, tid, 0);
    stage_u16_half(Kh + k0, 512, BsH, tid, 1);
    stage_u16_half(Ql + k0, 512, BsL, tid, 0);
    stage_u16_half(Kl + k0, 512, BsL, tid, 1);
    __syncthreads();
    mma_split(AsH, AsL, BsH, BsL, wr, wc, m, quad, acc);
  }
  float* dst = wc ? MK : MQ;
  const int row0 = blockIdx.x * 128 + wr * 64 + quad * 4;
#pragma unroll
  for (int rt = 0; rt < 4; ++rt)
#pragma unroll
    for (int ct = 0; ct < 4; ++ct) {
      int d = (ct * 16 + m) & 63;
#pragma unroll
      for (int rg = 0; rg < 4; ++rg) {
        int row = row0 + rt * 16 + rg;
        dst[((size_t)nl * 1024 + row) * 64 + d] = acc[rt][ct][rg];
      }
    }
}

// ------ logits: qb.kb (bf16,K64) + MQ.MK^T (Dekker,K64) + C1r.Mf^T (fp16,K512) + rel --
// L stored fp16. blockIdx x/y SWAPPED vs grid meaning: x = q-tile so the 8
// k-sweep blocks of one q-panel share an XCD L2 (dispatch round-robins on x).
__global__ __launch_bounds__(256) void logits_kernel(const u16* __restrict__ qb, const u16* __restrict__ kb,
                                                     const float* __restrict__ MQ, const float* __restrict__ MK,
                                                     const u16* __restrict__ C1r, const u16* __restrict__ Mf,
                                                     const float* __restrict__ Rb, u16* __restrict__ L,
                                                     int n0) {
  __shared__ __align__(16) u16 AsH[4096], AsL[4096], BsH[4096], BsL[4096];
  const int tid = threadIdx.x, nl = blockIdx.z, n = n0 + nl, b = n >> 4;
  const int bq = blockIdx.x, bk = blockIdx.y;   // swapped for XCD L2 locality
  const int lane = tid & 63, wv = tid >> 6, wr = wv >> 1, wc = wv & 1;
  const int m = lane & 15, quad = lane >> 4;
  const size_t qa = ((size_t)n * 1024 + bq * 128) * 64;
  const size_t ka = ((size_t)n * 1024 + bk * 128) * 64;
  const size_t mqa = ((size_t)nl * 1024 + bq * 128) * 64;
  const size_t mka = ((size_t)nl * 1024 + bk * 128) * 64;
  const size_t ca = ((size_t)nl * 1024 + bq * 128) * 512;
  const size_t ma = ((size_t)b * 1024 + bk * 128) * 512;
  floatx4 acc[4][4];
  acc_zero(acc);
  for (int k0 = 0; k0 < 64; k0 += 32) {  // content QK^T bpe (bf16)
    __syncthreads();
    stage_u16(qb + qa + k0, 64, AsH, tid);
    stage_u16(kb + ka + k0, 64, BsH, tid);
    __syncthreads();
    mma_bf16(AsH, BsH, wr, wc, m, quad, acc);
  }
  for (int k0 = 0; k0 < 64; k0 += 32) {  // (MQ)(MK)^T fused content (Dekker)
    __syncthreads();
    stage_f32_split(MQ + mqa + k0, 64, AsH, AsL, tid);
    stage_f32_split(MK + mka + k0, 64, BsH, BsL, tid);
    __syncthreads();
    mma_split(AsH, AsL, BsH, BsL, wr, wc, m, quad, acc);
  }
  for (int k0 = 0; k0 < 512; k0 += 32) {  // M Rel M^T part 2: C1r @ Mf^T (fp16)
    __syncthreads();
    stage_u16(C1r + ca + k0, 512, AsH, tid);
    stage_u16(Mf + ma + k0, 512, BsH, tid);
    __syncthreads();
    mma_f16(AsH, BsH, wr, wc, m, quad, acc);
  }
  const int q0 = bq * 128 + wr * 64 + quad * 4;
  const int k0c = bk * 128 + wc * 64 + m;
#pragma unroll
  for (int rt = 0; rt < 4; ++rt)
#pragma unroll
    for (int ct = 0; ct < 4; ++ct) {
      int kc = k0c + ct * 16;
#pragma unroll
      for (int rg = 0; rg < 4; ++rg) {
        int q = q0 + rt * 16 + rg;
        int id = kc - q; id = id < -16 ? -16 : (id > 16 ? 16 : id); id += 16;
        float val = acc[rt][ct][rg] + Rb[((size_t)n * 1024 + q) * 33 + id];
        L[((size_t)nl * 1024 + q) * 1024 + kc] = f2h_bits(val);
      }
    }
}

// ---------------- softmax + PV (online; fp16 logits in A-frag layout) ----------
__global__ __launch_bounds__(256) void softmax_pv_kernel(const u16* __restrict__ L,
                                                         const u16* __restrict__ VT,
                                                         u16* __restrict__ AO, int n0) {
  __shared__ __align__(16) u16 Vs[4][2048];
  const int tid = threadIdx.x, lane = tid & 63, wv = tid >> 6;
  const int m = lane & 15, quad = lane >> 4;
  const int nl = blockIdx.y, n = n0 + nl, qt = blockIdx.x;
  const int qrow = qt * 64 + wv * 16 + m;
  const u16* Lrow = L + ((size_t)nl * 1024 + qrow) * 1024;
  const u16* Vbase = VT + (size_t)n * 64 * 1024;
  float mi = -1e30f, li = 0.f;
  floatx4 O[4];
  floatx4 z = {0.f, 0.f, 0.f, 0.f};
#pragma unroll
  for (int dt = 0; dt < 4; ++dt) O[dt] = z;

  for (int kt = 0; kt < 8; ++kt) {
    __syncthreads();
#pragma unroll
    for (int ct = 0; ct < 4; ++ct) {
      int o = tid * 16;
      int r = o >> 6, c = (o >> 4) & 3, sc = c ^ ((r >> 1) & 3);
      __builtin_amdgcn_global_load_lds(GAS(Vbase + (size_t)r * 1024 + kt * 128 + ct * 32 + sc * 8),
                                       LAS((char*)Vs[ct] + o), 16, 0, 0);
    }
    __syncthreads();

    float vals[4][8];
#pragma unroll
    for (int ct = 0; ct < 4; ++ct) {
      union { short8 s; _Float16 h[8]; } u;
      u.s = *(const short8*)(Lrow + kt * 128 + ct * 32 + quad * 8);
#pragma unroll
      for (int j = 0; j < 8; ++j) vals[ct][j] = (float)u.h[j];
    }
    float tmax = vals[0][0];
#pragma unroll
    for (int ct = 0; ct < 4; ++ct)
#pragma unroll
      for (int j = 0; j < 8; ++j) tmax = fmaxf(tmax, vals[ct][j]);
    tmax = fmaxf(tmax, __shfl_xor(tmax, 16));
    tmax = fmaxf(tmax, __shfl_xor(tmax, 32));
    float mnew = fmaxf(mi, tmax);
    float alpha = __expf(mi - mnew);
    float pv[4][8];
    float tsum = 0.f;
#pragma unroll
    for (int ct = 0; ct < 4; ++ct)
#pragma unroll
      for (int j = 0; j < 8; ++j) { pv[ct][j] = __expf(vals[ct][j] - mnew); tsum += pv[ct][j]; }
    tsum += __shfl_xor(tsum, 16);
    tsum += __shfl_xor(tsum, 32);
    li = li * alpha + tsum;
    mi = mnew;

    float ar[4];
#pragma unroll
    for (int rg = 0; rg < 4; ++rg) ar[rg] = __shfl(alpha, quad * 4 + rg);
#pragma unroll
    for (int dt = 0; dt < 4; ++dt)
#pragma unroll
      for (int rg = 0; rg < 4; ++rg) O[dt][rg] *= ar[rg];

    short8 pf[4];
#pragma unroll
    for (int ct = 0; ct < 4; ++ct) {
      union { short8 s; u16 us[8]; } up;
#pragma unroll
      for (int j = 0; j < 8; ++j) up.us[j] = f2bf(pv[ct][j]);
      pf[ct] = up.s;
    }
#pragma unroll
    for (int ct = 0; ct < 4; ++ct)
#pragma unroll
      for (int dt = 0; dt < 4; ++dt) {
        short8 vf = frag_ld(Vs[ct], dt * 16 + m, quad);
        O[dt] = __builtin_amdgcn_mfma_f32_16x16x32_bf16(pf[ct], vf, O[dt], 0, 0, 0);
      }
  }

  float linv = 1.f / li;
  float lr[4];
#pragma unroll
  for (int rg = 0; rg < 4; ++rg) lr[rg] = __shfl(linv, quad * 4 + rg);
  const int b = n >> 4, h = n & 15;
#pragma unroll
  for (int dt = 0; dt < 4; ++dt)
#pragma unroll
    for (int rg = 0; rg < 4; ++rg) {
      int q = qt * 64 + wv * 16 + quad * 4 + rg;
      float ov = O[dt][rg] * lr[rg];
      AO[((size_t)q * 4 + b) * 1024 + h * 64 + dt * 16 + m] = f2bf(ov);
    }
}

// ---------------- output projection: out = AO @ Wo^T + bo  (fp32 out) ----------
__global__ __launch_bounds__(256) void outproj_kernel(const u16* __restrict__ AO, const float* __restrict__ Wo,
                                                      const u16* __restrict__ Wob, int prep,
                                                      const float* __restrict__ bo, float* __restrict__ out) {
  __shared__ __align__(16) u16 As[4096], Bs[4096];
  const int tid = threadIdx.x;
  const int lane = tid & 63, wv = tid >> 6, wr = wv >> 1, wc = wv & 1;
  const int m = lane & 15, quad = lane >> 4;
  const u16* A = AO + (size_t)blockIdx.y * 128 * 1024;
  const size_t brow = (size_t)blockIdx.x * 128 * 1024;
  floatx4 acc[4][4];
  acc_zero(acc);
  for (int k0 = 0; k0 < 1024; k0 += 32) {
    __syncthreads();
    stage_u16(A + k0, 1024, As, tid);
    if (prep) stage_u16(Wob + brow + k0, 1024, Bs, tid);
    else      stage_f32_bf(Wo + brow + k0, 1024, Bs, tid);
    __syncthreads();
    mma_bf16(As, Bs, wr, wc, m, quad, acc);
  }
  const int r0 = blockIdx.y * 128 + wr * 64 + quad * 4;
  const int c0 = blockIdx.x * 128 + wc * 64 + m;
#pragma unroll
  for (int rt = 0; rt < 4; ++rt)
#pragma unroll
    for (int ct = 0; ct < 4; ++ct) {
      int col = c0 + ct * 16;
      float bi = bo[col];
#pragma unroll
      for (int rg = 0; rg < 4; ++rg) {
        int row = r0 + rt * 16 + rg;
        out[(size_t)row * 1024 + col] = acc[rt][ct][rg] + bi;
      }
    }
}

extern "C" void kernel_launch(void* const* d_in, const int* in_sizes, int n_in,
                              void* d_out, int out_size, void* d_ws, size_t ws_size,
                              hipStream_t stream) {
  const float* query_bpe = (const float*)d_in[0];
  const float* query_word = (const float*)d_in[1];
  const float* mapping = (const float*)d_in[2];
  const float* Wq_bpe = (const float*)d_in[3];
  const float* bq_bpe = (const float*)d_in[4];
  const float* Wk_bpe = (const float*)d_in[5];
  const float* bk_bpe = (const float*)d_in[6];
  const float* Wq_word = (const float*)d_in[7];
  const float* bq_word = (const float*)d_in[8];
  const float* Wk_word = (const float*)d_in[9];
  const float* bk_word = (const float*)d_in[10];
  const float* Wv = (const float*)d_in[11];
  const float* bv = (const float*)d_in[12];
  const float* Wo = (const float*)d_in[13];
  const float* bo = (const float*)d_in[14];
  const float* relk = (const float*)d_in[15];

  char* ws = (char*)d_ws;
  size_t off = 0;
  u16* q_bpe = (u16*)(ws + off); off += 8388608;   // [64][1024][64] bf16
  u16* k_bpe = (u16*)(ws + off); off += 8388608;
  u16* VTb   = (u16*)(ws + off); off += 8388608;   // [64][64][1024] bf16
  u16* qwT_h = (u16*)(ws + off); off += 4194304;   // [64][64][512] bf16 hi (transposed)
  u16* qwT_l = (u16*)(ws + off); off += 4194304;
  u16* kwT_h = (u16*)(ws + off); off += 4194304;
  u16* kwT_l = (u16*)(ws + off); off += 4194304;
  u16* M_h   = (u16*)(ws + off); off += 4194304;   // [4][1024][512] bf16
  u16* M_l   = (u16*)(ws + off); off += 4194304;
  u16* M_f   = (u16*)(ws + off); off += 4194304;   // fp16
  float* R_word = (float*)(ws + off); off += 4325376;  // [64][512][33]
  float* R_bpe  = (float*)(ws + off); off += 8650752;  // [64][1024][33]
  u16* AO    = (u16*)(ws + off); off += 8388608;   // [4096][1024] bf16
  u16* Wo_bf = (u16*)(ws + off); off += 2097152;   // Wo bf16 (read at the very end)
  const size_t fixed_end = off;                    // ~79.6 MB

  // Union region: transient prep buffers (30 MB, dead after proj_all) overlap
  // the per-chunk loop buffers. Stream serialization makes this safe.
  const size_t avail = (ws_size > fixed_end) ? ws_size - fixed_end : 0;
  const int prep = avail >= 31457280 ? 1 : 0;
  // per-nl: RelT_win 64KB + PS 264KB + C1r 1MB + L 2MB + MQ 256KB + MK 256KB
  const size_t per_nc = 4005888;
  int NC = 1;
  for (int c = 64; c >= 1; c >>= 1) {
    if ((size_t)c * per_nc <= avail) { NC = c; break; }
  }
  char* vb = ws + fixed_end;
  // loop buffers
  u16* RelT  = (u16*)(vb);                                  // NC*65536
  float* PS  = (float*)(vb + (size_t)NC * 65536);           // NC*270336
  u16* C1r   = (u16*)(vb + (size_t)NC * 335872);            // NC*1048576
  u16* L_c   = (u16*)(vb + (size_t)NC * 1384448);           // NC*2097152
  float* MQ  = (float*)(vb + (size_t)NC * 3481600);         // NC*262144
  float* MK  = (float*)(vb + (size_t)NC * 3743744);         // NC*262144
  // prep buffers (same bytes, earlier in time)
  u16* Xb    = (u16*)(vb);               // 8 MB  query_bpe bf16
  u16* Wqb   = (u16*)(vb + 8388608);     // 2 MB
  u16* Wkb   = (u16*)(vb + 10485760);
  u16* Wvb   = (u16*)(vb + 12582912);
  u16* Xw_h  = (u16*)(vb + 14680064);    // 4 MB
  u16* Xw_l  = (u16*)(vb + 18874368);
  u16* Wqw_h = (u16*)(vb + 23068672);    // 2 MB
  u16* Wqw_l = (u16*)(vb + 25165824);
  u16* Wkw_h = (u16*)(vb + 27262976);
  u16* Wkw_l = (u16*)(vb + 29360128);    // end 30 MB

  if (prep) {
    CvtB cb = {};
    cb.src[0] = query_bpe; cb.dst[0] = Xb;    cb.n8[0] = 524288;
    cb.src[1] = Wq_bpe;    cb.dst[1] = Wqb;   cb.n8[1] = 131072;
    cb.src[2] = Wk_bpe;    cb.dst[2] = Wkb;   cb.n8[2] = 131072;
    cb.src[3] = Wv;        cb.dst[3] = Wvb;   cb.n8[3] = 131072;
    cb.src[4] = Wo;        cb.dst[4] = Wo_bf; cb.n8[4] = 131072;
    cvt_bf_kernel<<<dim3(2048, 1, 5), 256, 0, stream>>>(cb);
    CvtS cs = {};
    cs.src[0] = query_word; cs.dh[0] = Xw_h;  cs.dl[0] = Xw_l;  cs.n8[0] = 262144;
    cs.src[1] = Wq_word;    cs.dh[1] = Wqw_h; cs.dl[1] = Wqw_l; cs.n8[1] = 131072;
    cs.src[2] = Wk_word;    cs.dh[2] = Wkw_h; cs.dl[2] = Wkw_l; cs.n8[2] = 131072;
    cvt_split_kernel<<<dim3(1024, 1, 3), 256, 0, stream>>>(cs);
  }

  PAll pa = {};
  pa.prep = prep;
  pa.Xf[0] = query_bpe;  pa.Wf[0] = Wq_bpe;  pa.Xh[0] = Xb;   pa.Wh[0] = Wqb;
  pa.bias[0] = bq_bpe;  pa.scale[0] = 0.125f; pa.dh[0] = q_bpe; pa.T[0] = 1024; pa.md[0] = 0;
  pa.Xf[1] = query_bpe;  pa.Wf[1] = Wk_bpe;  pa.Xh[1] = Xb;   pa.Wh[1] = Wkb;
  pa.bias[1] = bk_bpe;  pa.scale[1] = 1.0f;   pa.dh[1] = k_bpe; pa.T[1] = 1024; pa.md[1] = 0;
  pa.Xf[2] = query_bpe;  pa.Wf[2] = Wv;      pa.Xh[2] = Xb;   pa.Wh[2] = Wvb;
  pa.bias[2] = bv;      pa.scale[2] = 1.0f;   pa.dh[2] = VTb;   pa.T[2] = 1024; pa.md[2] = 1;
  pa.Xf[3] = query_word; pa.Wf[3] = Wq_word; pa.Xh[3] = Xw_h; pa.Xl[3] = Xw_l;
  pa.Wh[3] = Wqw_h; pa.Wl[3] = Wqw_l;
  pa.bias[3] = bq_word; pa.scale[3] = 0.125f; pa.dh[3] = qwT_h; pa.dl[3] = qwT_l; pa.T[3] = 512; pa.md[3] = 2;
  pa.Xf[4] = query_word; pa.Wf[4] = Wk_word; pa.Xh[4] = Xw_h; pa.Xl[4] = Xw_l;
  pa.Wh[4] = Wkw_h; pa.Wl[4] = Wkw_l;
  pa.bias[4] = bk_word; pa.scale[4] = 1.0f;   pa.dh[4] = kwT_h; pa.dl[4] = kwT_l; pa.T[4] = 512; pa.md[4] = 2;
  proj_all_kernel<<<dim3(8, 32, 5), 256, 0, stream>>>(pa);

  msplit_kernel<<<dim3(4 * 1024 * 512 / 256), 256, 0, stream>>>(mapping, M_h, M_l, M_f);

  rel_bpe_kernel<<<dim3(64 * 1024 / 256), 256, 0, stream>>>(q_bpe, relk, R_bpe);
  rel_word_kernel<<<dim3(64 * 512 / 256), 256, 0, stream>>>(qwT_h, qwT_l, relk, R_word);

  for (int n0 = 0; n0 < 64; n0 += NC) {
    relmat64_kernel<<<dim3(NC * 16), 256, 0, stream>>>(R_word, RelT, n0);
    prefix16_kernel<<<dim3(4, NC), 256, 0, stream>>>(M_f, R_word, PS, n0);
    mqk_kernel<<<dim3(8, NC), 256, 0, stream>>>(M_h, M_l, qwT_h, qwT_l, kwT_h, kwT_l, MQ, MK, n0);
    stage1band_kernel<<<dim3(16, 8, NC), 256, 0, stream>>>(M_f, RelT, PS, C1r, n0);
    logits_kernel<<<dim3(8, 8, NC), 256, 0, stream>>>(q_bpe, k_bpe, MQ, MK, C1r, M_f, R_bpe, L_c, n0);
    softmax_pv_kernel<<<dim3(16, NC), 256, 0, stream>>>(L_c, VTb, AO, n0);
  }

  outproj_kernel<<<dim3(8, 32), 256, 0, stream>>>(AO, Wo, Wo_bf, prep, bo, (float*)d_out);
}

// Round 2
// 730.437 us; speedup vs baseline: 1.0508x; 1.0490x over previous
//
#include <hip/hip_runtime.h>

// RelativeBPEWORDFusionMultiheadAttention on MI355X (gfx950). FP32 in/out.
// Factorization: fused = (MQ)(MK)^T + M·Rel·M^T (content Dekker-bf16, Rel fp16).
// Round 11: (a) 2-phase double-buffered staging (issue next global_load_lds
// before computing current tile, ONE barrier per K-step) in logits/proj_all/
// outproj/softmax_pv — removes the serial stage->drain->compute latency that
// held MfmaUtil at ~16%. (b) proj_all md=1/2 epilogues transpose via LDS and
// store 64B-contiguous lines (old 2B scatter caused 105MB RFO fetch + 105MB
// write). (c) mqk emits MQ/MK pre-split bf16 h/l so logits loop2 is pure async.

#define DEV __device__ __forceinline__
#define GAS(x) ((const __attribute__((address_space(1))) unsigned*)(x))
#define LAS(x) ((__attribute__((address_space(3))) unsigned*)(x))

typedef unsigned short u16;
typedef __attribute__((ext_vector_type(8))) short short8;
typedef __attribute__((ext_vector_type(8))) _Float16 half8;
typedef __attribute__((ext_vector_type(4))) float floatx4;

DEV float bf2f(u16 u) { union { unsigned u; float f; } v; v.u = ((unsigned)u) << 16; return v.f; }
DEV u16 f2bf(float f) {
  union { float f; unsigned u; } v; v.f = f;
  unsigned r = v.u + 0x7FFFu + ((v.u >> 16) & 1u);  // RNE
  return (u16)(r >> 16);
}
DEV u16 f2h_bits(float f) { union { _Float16 h; u16 u; } v; v.h = (_Float16)f; return v.u; }

// ---- LDS tile [128][32] u16, 16B-chunk XOR swizzle (source-side permute) ----
DEV void stage_u16(const u16* g, int ld, u16* lds, int tid) {
#pragma unroll
  for (int p = 0; p < 2; ++p) {
    int o = (p * 256 + tid) * 16;
    int r = o >> 6, c = (o >> 4) & 3, sc = c ^ ((r >> 1) & 3);
    __builtin_amdgcn_global_load_lds(GAS(g + (size_t)r * ld + sc * 8),
                                     LAS((char*)lds + o), 16, 0, 0);
  }
}

DEV void stage_u16_half(const u16* g, int ld, u16* lds, int tid, int p) {
  int o = (p * 256 + tid) * 16;
  int r = o >> 6, c = (o >> 4) & 3, sc = c ^ ((r >> 1) & 3);
  __builtin_amdgcn_global_load_lds(GAS(g + (size_t)(r - p * 64) * ld + sc * 8),
                                   LAS((char*)lds + o), 16, 0, 0);
}

DEV void stage_f32_bf(const float* g, int ld, u16* lds, int tid) {
#pragma unroll
  for (int p = 0; p < 2; ++p) {
    int o = (p * 256 + tid) * 16;
    int r = o >> 6, c = (o >> 4) & 3, sc = c ^ ((r >> 1) & 3);
    const float* src = g + (size_t)r * ld + sc * 8;
    union { short8 s; u16 u[8]; } oh;
#pragma unroll
    for (int j = 0; j < 8; ++j) oh.u[j] = f2bf(src[j]);
    *(short8*)((char*)lds + o) = oh.s;
  }
}

DEV void stage_f32_split(const float* g, int ld, u16* ldsh, u16* ldsl, int tid) {
#pragma unroll
  for (int p = 0; p < 2; ++p) {
    int o = (p * 256 + tid) * 16;
    int r = o >> 6, c = (o >> 4) & 3, sc = c ^ ((r >> 1) & 3);
    const float* src = g + (size_t)r * ld + sc * 8;
    union { short8 s; u16 u[8]; } oh, ol;
#pragma unroll
    for (int j = 0; j < 8; ++j) {
      float f = src[j];
      u16 h = f2bf(f);
      oh.u[j] = h;
      ol.u[j] = f2bf(f - bf2f(h));
    }
    *(short8*)((char*)ldsh + o) = oh.s;
    *(short8*)((char*)ldsl + o) = ol.s;
  }
}

DEV short8 frag_ld(const u16* lds, int row, int quad) {
  int c = quad ^ ((row >> 1) & 3);
  return *(const short8*)(lds + row * 32 + c * 8);
}

DEV void mma_bf16(const u16* As, const u16* Bs, int wr, int wc, int m, int quad, floatx4 acc[4][4]) {
  short8 af[4], bf[4];
#pragma unroll
  for (int t = 0; t < 4; ++t) af[t] = frag_ld(As, wr * 64 + t * 16 + m, quad);
#pragma unroll
  for (int t = 0; t < 4; ++t) bf[t] = frag_ld(Bs, wc * 64 + t * 16 + m, quad);
#pragma unroll
  for (int rt = 0; rt < 4; ++rt)
#pragma unroll
    for (int ct = 0; ct < 4; ++ct)
      acc[rt][ct] = __builtin_amdgcn_mfma_f32_16x16x32_bf16(af[rt], bf[ct], acc[rt][ct], 0, 0, 0);
}

DEV void mma_f16(const u16* As, const u16* Bs, int wr, int wc, int m, int quad, floatx4 acc[4][4]) {
  union { short8 s; half8 h; } af[4], bf[4];
#pragma unroll
  for (int t = 0; t < 4; ++t) af[t].s = frag_ld(As, wr * 64 + t * 16 + m, quad);
#pragma unroll
  for (int t = 0; t < 4; ++t) bf[t].s = frag_ld(Bs, wc * 64 + t * 16 + m, quad);
#pragma unroll
  for (int rt = 0; rt < 4; ++rt)
#pragma unroll
    for (int ct = 0; ct < 4; ++ct)
      acc[rt][ct] = __builtin_amdgcn_mfma_f32_16x16x32_f16(af[rt].h, bf[ct].h, acc[rt][ct], 0, 0, 0);
}

// Dekker 3-pass: hh + hl + lh (bf16 operands, ~2^-16 effective)
DEV void mma_split(const u16* AsH, const u16* AsL, const u16* BsH, const u16* BsL,
                   int wr, int wc, int m, int quad, floatx4 acc[4][4]) {
  short8 ah[4], al[4], bh[4], bl[4];
#pragma unroll
  for (int t = 0; t < 4; ++t) {
    ah[t] = frag_ld(AsH, wr * 64 + t * 16 + m, quad);
    al[t] = frag_ld(AsL, wr * 64 + t * 16 + m, quad);
    bh[t] = frag_ld(BsH, wc * 64 + t * 16 + m, quad);
    bl[t] = frag_ld(BsL, wc * 64 + t * 16 + m, quad);
  }
#pragma unroll
  for (int rt = 0; rt < 4; ++rt)
#pragma unroll
    for (int ct = 0; ct < 4; ++ct) {
      acc[rt][ct] = __builtin_amdgcn_mfma_f32_16x16x32_bf16(ah[rt], bh[ct], acc[rt][ct], 0, 0, 0);
      acc[rt][ct] = __builtin_amdgcn_mfma_f32_16x16x32_bf16(ah[rt], bl[ct], acc[rt][ct], 0, 0, 0);
      acc[rt][ct] = __builtin_amdgcn_mfma_f32_16x16x32_bf16(al[rt], bh[ct], acc[rt][ct], 0, 0, 0);
    }
}

DEV void acc_zero(floatx4 acc[4][4]) {
  floatx4 z = {0.f, 0.f, 0.f, 0.f};
#pragma unroll
  for (int i = 0; i < 4; ++i)
#pragma unroll
    for (int j = 0; j < 4; ++j) acc[i][j] = z;
}

// ---------------- input pre-conversion ----------------
struct CvtB { const float* src[5]; u16* dst[5]; int n8[5]; };
__global__ __launch_bounds__(256) void cvt_bf_kernel(CvtB a) {
  int z = blockIdx.z;
  int i = blockIdx.x * 256 + threadIdx.x;
  if (i >= a.n8[z]) return;
  const float* s = a.src[z] + (size_t)i * 8;
  union { short8 v; u16 u[8]; } o;
#pragma unroll
  for (int j = 0; j < 8; ++j) o.u[j] = f2bf(s[j]);
  *(short8*)(a.dst[z] + (size_t)i * 8) = o.v;
}

struct CvtS { const float* src[3]; u16* dh[3]; u16* dl[3]; int n8[3]; };
__global__ __launch_bounds__(256) void cvt_split_kernel(CvtS a) {
  int z = blockIdx.z;
  int i = blockIdx.x * 256 + threadIdx.x;
  if (i >= a.n8[z]) return;
  const float* s = a.src[z] + (size_t)i * 8;
  union { short8 v; u16 u[8]; } oh, ol;
#pragma unroll
  for (int j = 0; j < 8; ++j) {
    float f = s[j];
    u16 h = f2bf(f);
    oh.u[j] = h;
    ol.u[j] = f2bf(f - bf2f(h));
  }
  *(short8*)(a.dh[z] + (size_t)i * 8) = oh.v;
  *(short8*)(a.dl[z] + (size_t)i * 8) = ol.v;
}

// ---------------- all 5 projections, one launch ----------------
// z: 0=q_bpe(bf16) 1=k_bpe(bf16) 2=V->VT(bf16) 3=q_word(Dekker->transposed h/l)
//    4=k_word(Dekker->transposed h/l)
struct PAll {
  const float* Xf[5]; const float* Wf[5];
  const u16* Xh[5]; const u16* Xl[5]; const u16* Wh[5]; const u16* Wl[5];
  const float* bias[5]; float scale[5];
  u16* dh[5]; u16* dl[5]; int T[5]; int md[5]; int prep;
};

__global__ __launch_bounds__(256) void proj_all_kernel(PAll a) {
  const int z = blockIdx.z;
  const int T = a.T[z];
  if ((int)blockIdx.y >= (T >> 5)) return;
  __shared__ __align__(16) u16 LB[8][4096];  // 64 KB pool: dbuf K-loop, then transpose
  const int tid = threadIdx.x;
  const int lane = tid & 63, wv = tid >> 6, wr = wv >> 1, wc = wv & 1;
  const int m = lane & 15, quad = lane >> 4;
  const int md = a.md[z], prep = a.prep;
  const int bx = blockIdx.x, by = blockIdx.y;
  const size_t arow = (size_t)by * 128 * 1024;
  const size_t brow = (size_t)bx * 128 * 1024;
  floatx4 acc[4][4];
  acc_zero(acc);
  if (prep) {
    // 2-phase dbuf: even k0 -> LB[0],LB[2](,LB[4],LB[6]); odd -> LB[1],LB[3](,LB[5],LB[7])
    if (md == 2) {
      stage_u16(a.Xh[z] + arow, 1024, LB[0], tid);
      stage_u16(a.Wh[z] + brow, 1024, LB[2], tid);
      stage_u16(a.Xl[z] + arow, 1024, LB[4], tid);
      stage_u16(a.Wl[z] + brow, 1024, LB[6], tid);
    } else {
      stage_u16(a.Xh[z] + arow, 1024, LB[0], tid);
      stage_u16(a.Wh[z] + brow, 1024, LB[2], tid);
    }
    __syncthreads();
    for (int k0 = 0; k0 < 1024; k0 += 32) {
      int cur = (k0 >> 5) & 1, nx = cur ^ 1;
      if (k0 + 32 < 1024) {
        if (md == 2) {
          stage_u16(a.Xh[z] + arow + k0 + 32, 1024, LB[nx], tid);
          stage_u16(a.Wh[z] + brow + k0 + 32, 1024, LB[2 + nx], tid);
          stage_u16(a.Xl[z] + arow + k0 + 32, 1024, LB[4 + nx], tid);
          stage_u16(a.Wl[z] + brow + k0 + 32, 1024, LB[6 + nx], tid);
        } else {
          stage_u16(a.Xh[z] + arow + k0 + 32, 1024, LB[nx], tid);
          stage_u16(a.Wh[z] + brow + k0 + 32, 1024, LB[2 + nx], tid);
        }
      }
      if (md == 2) mma_split(LB[cur], LB[4 + cur], LB[2 + cur], LB[6 + cur], wr, wc, m, quad, acc);
      else         mma_bf16(LB[cur], LB[2 + cur], wr, wc, m, quad, acc);
      __syncthreads();
    }
  } else {
    for (int k0 = 0; k0 < 1024; k0 += 32) {
      __syncthreads();
      if (md == 2) {
        stage_f32_split(a.Xf[z] + arow + k0, 1024, LB[0], LB[4], tid);
        stage_f32_split(a.Wf[z] + brow + k0, 1024, LB[2], LB[6], tid);
      } else {
        stage_f32_bf(a.Xf[z] + arow + k0, 1024, LB[0], tid);
        stage_f32_bf(a.Wf[z] + brow + k0, 1024, LB[2], tid);
      }
      __syncthreads();
      if (md == 2) mma_split(LB[0], LB[4], LB[2], LB[6], wr, wc, m, quad, acc);
      else         mma_bf16(LB[0], LB[2], wr, wc, m, quad, acc);
    }
    __syncthreads();
  }
  const float scale = a.scale[z];
  const float* bias = a.bias[z];
  u16* dh = a.dh[z];
  u16* dl = a.dl[z];
  const int row0l = wr * 64 + quad * 4;
  const int col0l = wc * 64 + m;
  if (md == 0) {
#pragma unroll
    for (int rt = 0; rt < 4; ++rt)
#pragma unroll
      for (int ct = 0; ct < 4; ++ct) {
        int col = bx * 128 + col0l + ct * 16;
        float bi = bias[col];
        int h = col >> 6, d = col & 63;
#pragma unroll
        for (int rg = 0; rg < 4; ++rg) {
          int row = by * 128 + row0l + rt * 16 + rg;
          int t = row >> 2, bb = row & 3, n = bb * 16 + h;
          float val = (acc[rt][ct][rg] + bi) * scale;
          dh[((size_t)n * T + t) * 64 + d] = f2bf(val);
        }
      }
  } else if (md == 1) {
    // transpose via LDS, emit 64B-contiguous stores to VT[n][d][t]
    u16* TB = (u16*)LB;  // [128 cols][stride 130 rows] u16 (33280 B)
    __syncthreads();
#pragma unroll
    for (int rt = 0; rt < 4; ++rt)
#pragma unroll
      for (int ct = 0; ct < 4; ++ct) {
        int cl = col0l + ct * 16;
        float bi = bias[bx * 128 + cl];
#pragma unroll
        for (int rg = 0; rg < 4; ++rg) {
          int rl = row0l + rt * 16 + rg;
          TB[(size_t)cl * 130 + rl] = f2bf((acc[rt][ct][rg] + bi) * scale);
        }
      }
    __syncthreads();
    for (int task = tid; task < 512; task += 256) {
      int c = task & 127, bb = task >> 7;
      int colg = bx * 128 + c, h = colg >> 6, d = colg & 63;
      size_t base = (((size_t)(bb * 16 + h)) * 64 + d) * 1024 + (size_t)by * 32;
#pragma unroll
      for (int g = 0; g < 4; ++g) {
        union { short8 v; u16 u[8]; } o;
#pragma unroll
        for (int j = 0; j < 8; ++j) o.u[j] = TB[(size_t)c * 130 + bb + 4 * (g * 8 + j)];
        *(short8*)(dh + base + g * 8) = o.v;
      }
    }
  } else {
    // md==2: Dekker h/l transposed stores, two col-half passes
    u16* TBh = (u16*)LB;          // [64][130]
    u16* TBl = TBh + 64 * 130;
    for (int pass = 0; pass < 2; ++pass) {
      __syncthreads();
      if (wc == pass) {
#pragma unroll
        for (int rt = 0; rt < 4; ++rt)
#pragma unroll
          for (int ct = 0; ct < 4; ++ct) {
            int cl = ct * 16 + m;
            float bi = bias[bx * 128 + pass * 64 + cl];
#pragma unroll
            for (int rg = 0; rg < 4; ++rg) {
              int rl = row0l + rt * 16 + rg;
              float val = (acc[rt][ct][rg] + bi) * scale;
              u16 hh = f2bf(val);
              TBh[(size_t)cl * 130 + rl] = hh;
              TBl[(size_t)cl * 130 + rl] = f2bf(val - bf2f(hh));
            }
          }
      }
      __syncthreads();
      int c2 = tid & 63, bb = tid >> 6;
      int colg = bx * 128 + pass * 64 + c2, h = colg >> 6, d = colg & 63;
      size_t base = (((size_t)(bb * 16 + h)) * 64 + d) * 512 + (size_t)by * 32;
#pragma unroll
      for (int g = 0; g < 4; ++g) {
        union { short8 v; u16 u[8]; } oh, ol;
#pragma unroll
        for (int j = 0; j < 8; ++j) {
          oh.u[j] = TBh[(size_t)c2 * 130 + bb + 4 * (g * 8 + j)];
          ol.u[j] = TBl[(size_t)c2 * 130 + bb + 4 * (g * 8 + j)];
        }
        *(short8*)(dh + base + g * 8) = oh.v;
        *(short8*)(dl + base + g * 8) = ol.v;
      }
    }
  }
}

// ---------------- M -> Mh,Ml (bf16 Dekker) + Mf (fp16) ----------------
__global__ __launch_bounds__(256) void msplit_kernel(const float* __restrict__ M,
                                                     u16* __restrict__ Mh, u16* __restrict__ Ml,
                                                     u16* __restrict__ Mf) {
  int i = blockIdx.x * 256 + threadIdx.x;
  float f = M[i];
  u16 h = f2bf(f);
  Mh[i] = h;
  Ml[i] = f2bf(f - bf2f(h));
  Mf[i] = f2h_bits(f);
}

// ---------------- rel tables ----------------
__global__ __launch_bounds__(256) void rel_bpe_kernel(const u16* __restrict__ q,
                                                      const float* __restrict__ relk,
                                                      float* __restrict__ R) {
  int nt = blockIdx.x * 256 + threadIdx.x;
  float qv[64];
#pragma unroll
  for (int c = 0; c < 8; ++c) {
    union { short8 s; u16 u[8]; } uh; uh.s = *(const short8*)(q + (size_t)nt * 64 + c * 8);
#pragma unroll
    for (int j = 0; j < 8; ++j) qv[c * 8 + j] = bf2f(uh.u[j]);
  }
  for (int r = 0; r < 33; ++r) {
    const float* krow = relk + r * 64;
    float s = 0.f;
#pragma unroll
    for (int d = 0; d < 64; ++d) s += qv[d] * krow[d];
    R[(size_t)nt * 33 + r] = s;
  }
}

__global__ __launch_bounds__(256) void rel_word_kernel(const u16* __restrict__ qh, const u16* __restrict__ ql,
                                                       const float* __restrict__ relk,
                                                       float* __restrict__ R) {
  int nt = blockIdx.x * 256 + threadIdx.x;
  int n = nt >> 9, w = nt & 511;
  float qv[64];
#pragma unroll
  for (int d = 0; d < 64; ++d) {
    size_t idx = ((size_t)n * 64 + d) * 512 + w;
    qv[d] = bf2f(qh[idx]) + bf2f(ql[idx]);
  }
  for (int r = 0; r < 33; ++r) {
    const float* krow = relk + r * 64;
    float s = 0.f;
#pragma unroll
    for (int d = 0; d < 64; ++d) s += qv[d] * krow[d];
    R[(size_t)nt * 33 + r] = s;
  }
}

// ---- RelT_win build: 64-wide windowed Rel tiles, fp16 -----------------------
__global__ __launch_bounds__(256) void relmat64_kernel(const float* __restrict__ Rw,
                                                       u16* __restrict__ RT, int n0) {
  int i = blockIdx.x * 256 + threadIdx.x;            // NC*16*32*8 short8 items
  int w8 = i & 7, s = (i >> 3) & 31, t = (i >> 8) & 15, nl = i >> 12;
  int n = n0 + nl;
  int w0 = (t == 0) ? 0 : (t == 15 ? 448 : 32 * t - 16);
  int sg = t * 32 + s;
  const float* R = Rw + (size_t)n * 512 * 33;
  union { short8 v; u16 u[8]; } o;
#pragma unroll
  for (int j = 0; j < 8; ++j) {
    int w = w0 + w8 * 8 + j;
    int d = sg - w; d = d < -16 ? -16 : (d > 16 ? 16 : d);
    o.u[j] = f2h_bits(R[(size_t)w * 33 + d + 16]);
  }
  *(short8*)(RT + (size_t)i * 8) = o.v;
}

// ---- coarse prefixes: PS[nl][q][0..32]=sum_{w<16i} Mf*R[w][32]  (PreA)
//                       PS[nl][q][33+i] =sum_{w>=16i} Mf*R[w][0]  (SufB)
__global__ __launch_bounds__(256) void prefix16_kernel(const u16* __restrict__ Mf,
                                                       const float* __restrict__ Rw,
                                                       float* __restrict__ PS, int n0) {
  const int nl = blockIdx.y, n = n0 + nl, b = n >> 4;
  const int q = blockIdx.x * 256 + threadIdx.x;
  const u16* mrow = Mf + ((size_t)b * 1024 + q) * 512;
  const float* R = Rw + (size_t)n * 512 * 33;
  float* ps = PS + ((size_t)nl * 1024 + q) * 66;
  float blkA[32], blkB[32];
#pragma unroll
  for (int t = 0; t < 32; ++t) {
    float a = 0.f, bb = 0.f;
#pragma unroll
    for (int c = 0; c < 2; ++c) {
      union { short8 s; _Float16 h[8]; } u;
      u.s = *(const short8*)(mrow + t * 16 + c * 8);
#pragma unroll
      for (int j = 0; j < 8; ++j) {
        int w = t * 16 + c * 8 + j;
        float mv = (float)u.h[j];
        a += mv * R[(size_t)w * 33 + 32];
        bb += mv * R[(size_t)w * 33];
      }
    }
    blkA[t] = a; blkB[t] = bb;
  }
  float run = 0.f;
#pragma unroll
  for (int i = 0; i < 33; ++i) { ps[i] = run; if (i < 32) run += blkA[i]; }
  float tot = 0.f;
#pragma unroll
  for (int i = 0; i < 32; ++i) tot += blkB[i];
  run = tot;
#pragma unroll
  for (int i = 0; i < 33; ++i) { ps[33 + i] = run; if (i < 32) run -= blkB[i]; }
}

// ---- stage1 band: C1r[nl][q][s] = K=64 windowed MFMA + alpha[q] + beta[q] ----
__global__ __launch_bounds__(256) void stage1band_kernel(const u16* __restrict__ Mf,
                                                         const u16* __restrict__ RT,
                                                         const float* __restrict__ PS,
                                                         u16* __restrict__ C1r, int n0) {
  __shared__ __align__(16) u16 As[4096], Bs[1024];
  const int tid = threadIdx.x, t = blockIdx.x, nl = blockIdx.z, n = n0 + nl, b = n >> 4;
  const int lane = tid & 63, wv = tid >> 6;
  const int m = lane & 15, quad = lane >> 4;
  const int w0 = (t == 0) ? 0 : (t == 15 ? 448 : 32 * t - 16);
  const size_t ma = ((size_t)b * 1024 + blockIdx.y * 128) * 512 + w0;
  const u16* rt = RT + ((size_t)nl * 16 + t) * 2048;
  floatx4 acc[2][2];
  floatx4 z = {0.f, 0.f, 0.f, 0.f};
  acc[0][0] = z; acc[0][1] = z; acc[1][0] = z; acc[1][1] = z;
#pragma unroll
  for (int k0 = 0; k0 < 64; k0 += 32) {
    __syncthreads();
    stage_u16(Mf + ma + k0, 512, As, tid);
    if (tid < 128) {
      int o = tid * 16;
      int r = o >> 6, c = (o >> 4) & 3, sc = c ^ ((r >> 1) & 3);
      __builtin_amdgcn_global_load_lds(GAS(rt + k0 + (size_t)r * 64 + sc * 8),
                                       LAS((char*)Bs + o), 16, 0, 0);
    }
    __syncthreads();
    union { short8 s; half8 h; } af[2], bf[2];
#pragma unroll
    for (int i = 0; i < 2; ++i) af[i].s = frag_ld(As, wv * 32 + i * 16 + m, quad);
#pragma unroll
    for (int i = 0; i < 2; ++i) bf[i].s = frag_ld(Bs, i * 16 + m, quad);
#pragma unroll
    for (int i = 0; i < 2; ++i)
#pragma unroll
      for (int j = 0; j < 2; ++j)
        acc[i][j] = __builtin_amdgcn_mfma_f32_16x16x32_f16(af[i].h, bf[j].h, acc[i][j], 0, 0, 0);
  }
  const int ia = w0 >> 4, ib = (w0 + 64) >> 4;
  const float* ps = PS + ((size_t)nl * 1024 + blockIdx.y * 128) * 66;
#pragma unroll
  for (int i = 0; i < 2; ++i)
#pragma unroll
    for (int rg = 0; rg < 4; ++rg) {
      int row = wv * 32 + i * 16 + quad * 4 + rg;
      float ab = ps[(size_t)row * 66 + ia] + ps[(size_t)row * 66 + 33 + ib];
      int q = blockIdx.y * 128 + row;
#pragma unroll
      for (int j = 0; j < 2; ++j) {
        int s = t * 32 + j * 16 + m;
        C1r[((size_t)nl * 1024 + q) * 512 + s] = f2h_bits(acc[i][j][rg] + ab);
      }
    }
}

// ---------------- MQ/MK: [1024,64] = M[1024,512] x {Q,K}^T, Dekker 3-pass ------
// Output pre-split as bf16 h/l pairs so logits can stage them async.
__global__ __launch_bounds__(256) void mqk_kernel(const u16* __restrict__ Mh, const u16* __restrict__ Ml,
                                                  const u16* __restrict__ qwTh, const u16* __restrict__ qwTl,
                                                  const u16* __restrict__ kwTh, const u16* __restrict__ kwTl,
                                                  u16* __restrict__ MQh, u16* __restrict__ MQl,
                                                  u16* __restrict__ MKh, u16* __restrict__ MKl, int n0) {
  __shared__ __align__(16) u16 AsH[4096], AsL[4096], BsH[4096], BsL[4096];
  const int tid = threadIdx.x, nl = blockIdx.y, n = n0 + nl, b = n >> 4;
  const int lane = tid & 63, wv = tid >> 6, wr = wv >> 1, wc = wv & 1;
  const int m = lane & 15, quad = lane >> 4;
  const size_t ma = ((size_t)b * 1024 + blockIdx.x * 128) * 512;
  const u16* Qh = qwTh + (size_t)n * 32768;
  const u16* Ql = qwTl + (size_t)n * 32768;
  const u16* Kh = kwTh + (size_t)n * 32768;
  const u16* Kl = kwTl + (size_t)n * 32768;
  floatx4 acc[4][4];
  acc_zero(acc);
  for (int k0 = 0; k0 < 512; k0 += 32) {
    __syncthreads();
    stage_u16(Mh + ma + k0, 512, AsH, tid);
    stage_u16(Ml + ma + k0, 512, AsL, tid);
    stage_u16_half(Qh + k0, 512, BsH, tid, 0);
    stage_u16_half(Kh + k0, 512, BsH, tid, 1);
    stage_u16_half(Ql + k0, 512, BsL, tid, 0);
    stage_u16_half(Kl + k0, 512, BsL, tid, 1);
    __syncthreads();
    mma_split(AsH, AsL, BsH, BsL, wr, wc, m, quad, acc);
  }
  u16* dsth = wc ? MKh : MQh;
  u16* dstl = wc ? MKl : MQl;
  const int row0 = blockIdx.x * 128 + wr * 64 + quad * 4;
#pragma unroll
  for (int rt = 0; rt < 4; ++rt)
#pragma unroll
    for (int ct = 0; ct < 4; ++ct) {
      int d = (ct * 16 + m) & 63;
#pragma unroll
      for (int rg = 0; rg < 4; ++rg) {
        int row = row0 + rt * 16 + rg;
        size_t idx = ((size_t)nl * 1024 + row) * 64 + d;
        float val = acc[rt][ct][rg];
        u16 hh = f2bf(val);
        dsth[idx] = hh;
        dstl[idx] = f2bf(val - bf2f(hh));
      }
    }
}

// ------ logits: qb.kb (bf16,K64) + MQ.MK^T (Dekker,K64) + C1r.Mf^T (fp16,K512) + rel --
// L stored fp16. x = q-tile (XCD L2 locality). 2-phase dbuf staging throughout.
__global__ __launch_bounds__(256) void logits_kernel(const u16* __restrict__ qb, const u16* __restrict__ kb,
                                                     const u16* __restrict__ MQh, const u16* __restrict__ MQl,
                                                     const u16* __restrict__ MKh, const u16* __restrict__ MKl,
                                                     const u16* __restrict__ C1r, const u16* __restrict__ Mf,
                                                     const float* __restrict__ Rb, u16* __restrict__ L,
                                                     int n0) {
  __shared__ __align__(16) u16 LB[8][4096];
  const int tid = threadIdx.x, nl = blockIdx.z, n = n0 + nl, b = n >> 4;
  const int bq = blockIdx.x, bk = blockIdx.y;   // x = q for XCD L2 locality
  const int lane = tid & 63, wv = tid >> 6, wr = wv >> 1, wc = wv & 1;
  const int m = lane & 15, quad = lane >> 4;
  const size_t qa = ((size_t)n * 1024 + bq * 128) * 64;
  const size_t ka = ((size_t)n * 1024 + bk * 128) * 64;
  const size_t mqa = ((size_t)nl * 1024 + bq * 128) * 64;
  const size_t mka = ((size_t)nl * 1024 + bk * 128) * 64;
  const size_t ca = ((size_t)nl * 1024 + bq * 128) * 512;
  const size_t ma = ((size_t)b * 1024 + bk * 128) * 512;
  floatx4 acc[4][4];
  acc_zero(acc);
  // loop1: content QK^T bpe (bf16, K=64) — dbuf
  stage_u16(qb + qa, 64, LB[0], tid);
  stage_u16(kb + ka, 64, LB[2], tid);
  __syncthreads();
  stage_u16(qb + qa + 32, 64, LB[1], tid);
  stage_u16(kb + ka + 32, 64, LB[3], tid);
  mma_bf16(LB[0], LB[2], wr, wc, m, quad, acc);
  __syncthreads();
  mma_bf16(LB[1], LB[3], wr, wc, m, quad, acc);
  __syncthreads();
  // loop2: (MQ)(MK)^T Dekker, K=64 — stage all 8 tiles at once, one barrier
  stage_u16(MQh + mqa,      64, LB[0], tid);
  stage_u16(MQh + mqa + 32, 64, LB[1], tid);
  stage_u16(MKh + mka,      64, LB[2], tid);
  stage_u16(MKh + mka + 32, 64, LB[3], tid);
  stage_u16(MQl + mqa,      64, LB[4], tid);
  stage_u16(MQl + mqa + 32, 64, LB[5], tid);
  stage_u16(MKl + mka,      64, LB[6], tid);
  stage_u16(MKl + mka + 32, 64, LB[7], tid);
  __syncthreads();
  mma_split(LB[0], LB[4], LB[2], LB[6], wr, wc, m, quad, acc);
  mma_split(LB[1], LB[5], LB[3], LB[7], wr, wc, m, quad, acc);
  __syncthreads();
  // loop3: M Rel M^T part 2: C1r @ Mf^T (fp16, K=512) — dbuf
  stage_u16(C1r + ca, 512, LB[0], tid);
  stage_u16(Mf + ma, 512, LB[2], tid);
  __syncthreads();
  for (int k0 = 0; k0 < 512; k0 += 32) {
    int cur = (k0 >> 5) & 1;
    if (k0 + 32 < 512) {
      stage_u16(C1r + ca + k0 + 32, 512, LB[cur ^ 1], tid);
      stage_u16(Mf + ma + k0 + 32, 512, LB[2 + (cur ^ 1)], tid);
    }
    mma_f16(LB[cur], LB[2 + cur], wr, wc, m, quad, acc);
    __syncthreads();
  }
  const int q0 = bq * 128 + wr * 64 + quad * 4;
  const int k0c = bk * 128 + wc * 64 + m;
#pragma unroll
  for (int rt = 0; rt < 4; ++rt)
#pragma unroll
    for (int ct = 0; ct < 4; ++ct) {
      int kc = k0c + ct * 16;
#pragma unroll
      for (int rg = 0; rg < 4; ++rg) {
        int q = q0 + rt * 16 + rg;
        int id = kc - q; id = id < -16 ? -16 : (id > 16 ? 16 : id); id += 16;
        float val = acc[rt][ct][rg] + Rb[((size_t)n * 1024 + q) * 33 + id];
        L[((size_t)nl * 1024 + q) * 1024 + kc] = f2h_bits(val);
      }
    }
}

// ---------------- softmax + PV (online; fp16 logits in A-frag layout) ----------
__global__ __launch_bounds__(256) void softmax_pv_kernel(const u16* __restrict__ L,
                                                         const u16* __restrict__ VT,
                                                         u16* __restrict__ AO, int n0) {
  __shared__ __align__(16) u16 Vs[2][4][2048];
  const int tid = threadIdx.x, lane = tid & 63, wv = tid >> 6;
  const int m = lane & 15, quad = lane >> 4;
  const int nl = blockIdx.y, n = n0 + nl, qt = blockIdx.x;
  const int qrow = qt * 64 + wv * 16 + m;
  const u16* Lrow = L + ((size_t)nl * 1024 + qrow) * 1024;
  const u16* Vbase = VT + (size_t)n * 64 * 1024;
  float mi = -1e30f, li = 0.f;
  floatx4 O[4];
  floatx4 z = {0.f, 0.f, 0.f, 0.f};
#pragma unroll
  for (int dt = 0; dt < 4; ++dt) O[dt] = z;

  auto stageV = [&](int kt, int buf) {
#pragma unroll
    for (int ct = 0; ct < 4; ++ct) {
      int o = tid * 16;
      int r = o >> 6, c = (o >> 4) & 3, sc = c ^ ((r >> 1) & 3);
      __builtin_amdgcn_global_load_lds(GAS(Vbase + (size_t)r * 1024 + kt * 128 + ct * 32 + sc * 8),
                                       LAS((char*)Vs[buf][ct] + o), 16, 0, 0);
    }
  };
  stageV(0, 0);
  __syncthreads();

  for (int kt = 0; kt < 8; ++kt) {
    int cur = kt & 1;
    if (kt + 1 < 8) stageV(kt + 1, cur ^ 1);

    float vals[4][8];
#pragma unroll
    for (int ct = 0; ct < 4; ++ct) {
      union { short8 s; _Float16 h[8]; } u;
      u.s = *(const short8*)(Lrow + kt * 128 + ct * 32 + quad * 8);
#pragma unroll
      for (int j = 0; j < 8; ++j) vals[ct][j] = (float)u.h[j];
    }
    float tmax = vals[0][0];
#pragma unroll
    for (int ct = 0; ct < 4; ++ct)
#pragma unroll
      for (int j = 0; j < 8; ++j) tmax = fmaxf(tmax, vals[ct][j]);
    tmax = fmaxf(tmax, __shfl_xor(tmax, 16));
    tmax = fmaxf(tmax, __shfl_xor(tmax, 32));
    float mnew = fmaxf(mi, tmax);
    float alpha = __expf(mi - mnew);
    float pv[4][8];
    float tsum = 0.f;
#pragma unroll
    for (int ct = 0; ct < 4; ++ct)
#pragma unroll
      for (int j = 0; j < 8; ++j) { pv[ct][j] = __expf(vals[ct][j] - mnew); tsum += pv[ct][j]; }
    tsum += __shfl_xor(tsum, 16);
    tsum += __shfl_xor(tsum, 32);
    li = li * alpha + tsum;
    mi = mnew;

    float ar[4];
#pragma unroll
    for (int rg = 0; rg < 4; ++rg) ar[rg] = __shfl(alpha, quad * 4 + rg);
#pragma unroll
    for (int dt = 0; dt < 4; ++dt)
#pragma unroll
      for (int rg = 0; rg < 4; ++rg) O[dt][rg] *= ar[rg];

    short8 pf[4];
#pragma unroll
    for (int ct = 0; ct < 4; ++ct) {
      union { short8 s; u16 us[8]; } up;
#pragma unroll
      for (int j = 0; j < 8; ++j) up.us[j] = f2bf(pv[ct][j]);
      pf[ct] = up.s;
    }
#pragma unroll
    for (int ct = 0; ct < 4; ++ct)
#pragma unroll
      for (int dt = 0; dt < 4; ++dt) {
        short8 vf = frag_ld(Vs[cur][ct], dt * 16 + m, quad);
        O[dt] = __builtin_amdgcn_mfma_f32_16x16x32_bf16(pf[ct], vf, O[dt], 0, 0, 0);
      }
    __syncthreads();
  }

  float linv = 1.f / li;
  float lr[4];
#pragma unroll
  for (int rg = 0; rg < 4; ++rg) lr[rg] = __shfl(linv, quad * 4 + rg);
  const int b = n >> 4, h = n & 15;
#pragma unroll
  for (int dt = 0; dt < 4; ++dt)
#pragma unroll
    for (int rg = 0; rg < 4; ++rg) {
      int q = qt * 64 + wv * 16 + quad * 4 + rg;
      float ov = O[dt][rg] * lr[rg];
      AO[((size_t)q * 4 + b) * 1024 + h * 64 + dt * 16 + m] = f2bf(ov);
    }
}

// ---------------- output projection: out = AO @ Wo^T + bo  (fp32 out) ----------
__global__ __launch_bounds__(256) void outproj_kernel(const u16* __restrict__ AO, const float* __restrict__ Wo,
                                                      const u16* __restrict__ Wob, int prep,
                                                      const float* __restrict__ bo, float* __restrict__ out) {
  __shared__ __align__(16) u16 LB[4][4096];
  const int tid = threadIdx.x;
  const int lane = tid & 63, wv = tid >> 6, wr = wv >> 1, wc = wv & 1;
  const int m = lane & 15, quad = lane >> 4;
  const u16* A = AO + (size_t)blockIdx.y * 128 * 1024;
  const size_t brow = (size_t)blockIdx.x * 128 * 1024;
  floatx4 acc[4][4];
  acc_zero(acc);
  if (prep) {
    stage_u16(A, 1024, LB[0], tid);
    stage_u16(Wob + brow, 1024, LB[2], tid);
    __syncthreads();
    for (int k0 = 0; k0 < 1024; k0 += 32) {
      int cur = (k0 >> 5) & 1;
      if (k0 + 32 < 1024) {
        stage_u16(A + k0 + 32, 1024, LB[cur ^ 1], tid);
        stage_u16(Wob + brow + k0 + 32, 1024, LB[2 + (cur ^ 1)], tid);
      }
      mma_bf16(LB[cur], LB[2 + cur], wr, wc, m, quad, acc);
      __syncthreads();
    }
  } else {
    for (int k0 = 0; k0 < 1024; k0 += 32) {
      __syncthreads();
      stage_u16(A + k0, 1024, LB[0], tid);
      stage_f32_bf(Wo + brow + k0, 1024, LB[2], tid);
      __syncthreads();
      mma_bf16(LB[0], LB[2], wr, wc, m, quad, acc);
    }
  }
  const int r0 = blockIdx.y * 128 + wr * 64 + quad * 4;
  const int c0 = blockIdx.x * 128 + wc * 64 + m;
#pragma unroll
  for (int rt = 0; rt < 4; ++rt)
#pragma unroll
    for (int ct = 0; ct < 4; ++ct) {
      int col = c0 + ct * 16;
      float bi = bo[col];
#pragma unroll
      for (int rg = 0; rg < 4; ++rg) {
        int row = r0 + rt * 16 + rg;
        out[(size_t)row * 1024 + col] = acc[rt][ct][rg] + bi;
      }
    }
}

extern "C" void kernel_launch(void* const* d_in, const int* in_sizes, int n_in,
                              void* d_out, int out_size, void* d_ws, size_t ws_size,
                              hipStream_t stream) {
  const float* query_bpe = (const float*)d_in[0];
  const float* query_word = (const float*)d_in[1];
  const float* mapping = (const float*)d_in[2];
  const float* Wq_bpe = (const float*)d_in[3];
  const float* bq_bpe = (const float*)d_in[4];
  const float* Wk_bpe = (const float*)d_in[5];
  const float* bk_bpe = (const float*)d_in[6];
  const float* Wq_word = (const float*)d_in[7];
  const float* bq_word = (const float*)d_in[8];
  const float* Wk_word = (const float*)d_in[9];
  const float* bk_word = (const float*)d_in[10];
  const float* Wv = (const float*)d_in[11];
  const float* bv = (const float*)d_in[12];
  const float* Wo = (const float*)d_in[13];
  const float* bo = (const float*)d_in[14];
  const float* relk = (const float*)d_in[15];

  char* ws = (char*)d_ws;
  size_t off = 0;
  u16* q_bpe = (u16*)(ws + off); off += 8388608;   // [64][1024][64] bf16
  u16* k_bpe = (u16*)(ws + off); off += 8388608;
  u16* VTb   = (u16*)(ws + off); off += 8388608;   // [64][64][1024] bf16
  u16* qwT_h = (u16*)(ws + off); off += 4194304;   // [64][64][512] bf16 hi (transposed)
  u16* qwT_l = (u16*)(ws + off); off += 4194304;
  u16* kwT_h = (u16*)(ws + off); off += 4194304;
  u16* kwT_l = (u16*)(ws + off); off += 4194304;
  u16* M_h   = (u16*)(ws + off); off += 4194304;   // [4][1024][512] bf16
  u16* M_l   = (u16*)(ws + off); off += 4194304;
  u16* M_f   = (u16*)(ws + off); off += 4194304;   // fp16
  float* R_word = (float*)(ws + off); off += 4325376;  // [64][512][33]
  float* R_bpe  = (float*)(ws + off); off += 8650752;  // [64][1024][33]
  u16* AO    = (u16*)(ws + off); off += 8388608;   // [4096][1024] bf16
  u16* Wo_bf = (u16*)(ws + off); off += 2097152;   // Wo bf16 (read at the very end)
  const size_t fixed_end = off;                    // ~79.6 MB

  // Union region: transient prep buffers (30 MB, dead after proj_all) overlap
  // the per-chunk loop buffers. Stream serialization makes this safe.
  const size_t avail = (ws_size > fixed_end) ? ws_size - fixed_end : 0;
  const int prep = avail >= 31457280 ? 1 : 0;
  // per-nl: RelT 64K + PS 264K + C1r 1M + L 2M + MQ/MK h+l 4x128K
  const size_t per_nc = 4005888;
  int NC = 1;
  for (int c = 64; c >= 1; c >>= 1) {
    if ((size_t)c * per_nc <= avail) { NC = c; break; }
  }
  char* vb = ws + fixed_end;
  // loop buffers
  u16* RelT  = (u16*)(vb);                                  // NC*65536
  float* PS  = (float*)(vb + (size_t)NC * 65536);           // NC*270336
  u16* C1r   = (u16*)(vb + (size_t)NC * 335872);            // NC*1048576
  u16* L_c   = (u16*)(vb + (size_t)NC * 1384448);           // NC*2097152
  u16* MQh   = (u16*)(vb + (size_t)NC * 3481600);           // NC*131072
  u16* MQl   = (u16*)(vb + (size_t)NC * 3612672);
  u16* MKh   = (u16*)(vb + (size_t)NC * 3743744);
  u16* MKl   = (u16*)(vb + (size_t)NC * 3874816);           // end NC*4005888
  // prep buffers (same bytes, earlier in time)
  u16* Xb    = (u16*)(vb);               // 8 MB  query_bpe bf16
  u16* Wqb   = (u16*)(vb + 8388608);     // 2 MB
  u16* Wkb   = (u16*)(vb + 10485760);
  u16* Wvb   = (u16*)(vb + 12582912);
  u16* Xw_h  = (u16*)(vb + 14680064);    // 4 MB
  u16* Xw_l  = (u16*)(vb + 18874368);
  u16* Wqw_h = (u16*)(vb + 23068672);    // 2 MB
  u16* Wqw_l = (u16*)(vb + 25165824);
  u16* Wkw_h = (u16*)(vb + 27262976);
  u16* Wkw_l = (u16*)(vb + 29360128);    // end 30 MB

  if (prep) {
    CvtB cb = {};
    cb.src[0] = query_bpe; cb.dst[0] = Xb;    cb.n8[0] = 524288;
    cb.src[1] = Wq_bpe;    cb.dst[1] = Wqb;   cb.n8[1] = 131072;
    cb.src[2] = Wk_bpe;    cb.dst[2] = Wkb;   cb.n8[2] = 131072;
    cb.src[3] = Wv;        cb.dst[3] = Wvb;   cb.n8[3] = 131072;
    cb.src[4] = Wo;        cb.dst[4] = Wo_bf; cb.n8[4] = 131072;
    cvt_bf_kernel<<<dim3(2048, 1, 5), 256, 0, stream>>>(cb);
    CvtS cs = {};
    cs.src[0] = query_word; cs.dh[0] = Xw_h;  cs.dl[0] = Xw_l;  cs.n8[0] = 262144;
    cs.src[1] = Wq_word;    cs.dh[1] = Wqw_h; cs.dl[1] = Wqw_l; cs.n8[1] = 131072;
    cs.src[2] = Wk_word;    cs.dh[2] = Wkw_h; cs.dl[2] = Wkw_l; cs.n8[2] = 131072;
    cvt_split_kernel<<<dim3(1024, 1, 3), 256, 0, stream>>>(cs);
  }

  PAll pa = {};
  pa.prep = prep;
  pa.Xf[0] = query_bpe;  pa.Wf[0] = Wq_bpe;  pa.Xh[0] = Xb;   pa.Wh[0] = Wqb;
  pa.bias[0] = bq_bpe;  pa.scale[0] = 0.125f; pa.dh[0] = q_bpe; pa.T[0] = 1024; pa.md[0] = 0;
  pa.Xf[1] = query_bpe;  pa.Wf[1] = Wk_bpe;  pa.Xh[1] = Xb;   pa.Wh[1] = Wkb;
  pa.bias[1] = bk_bpe;  pa.scale[1] = 1.0f;   pa.dh[1] = k_bpe; pa.T[1] = 1024; pa.md[1] = 0;
  pa.Xf[2] = query_bpe;  pa.Wf[2] = Wv;      pa.Xh[2] = Xb;   pa.Wh[2] = Wvb;
  pa.bias[2] = bv;      pa.scale[2] = 1.0f;   pa.dh[2] = VTb;   pa.T[2] = 1024; pa.md[2] = 1;
  pa.Xf[3] = query_word; pa.Wf[3] = Wq_word; pa.Xh[3] = Xw_h; pa.Xl[3] = Xw_l;
  pa.Wh[3] = Wqw_h; pa.Wl[3] = Wqw_l;
  pa.bias[3] = bq_word; pa.scale[3] = 0.125f; pa.dh[3] = qwT_h; pa.dl[3] = qwT_l; pa.T[3] = 512; pa.md[3] = 2;
  pa.Xf[4] = query_word; pa.Wf[4] = Wk_word; pa.Xh[4] = Xw_h; pa.Xl[4] = Xw_l;
  pa.Wh[4] = Wkw_h; pa.Wl[4] = Wkw_l;
  pa.bias[4] = bk_word; pa.scale[4] = 1.0f;   pa.dh[4] = kwT_h; pa.dl[4] = kwT_l; pa.T[4] = 512; pa.md[4] = 2;
  proj_all_kernel<<<dim3(8, 32, 5), 256, 0, stream>>>(pa);

  msplit_kernel<<<dim3(4 * 1024 * 512 / 256), 256, 0, stream>>>(mapping, M_h, M_l, M_f);

  rel_bpe_kernel<<<dim3(64 * 1024 / 256), 256, 0, stream>>>(q_bpe, relk, R_bpe);
  rel_word_kernel<<<dim3(64 * 512 / 256), 256, 0, stream>>>(qwT_h, qwT_l, relk, R_word);

  for (int n0 = 0; n0 < 64; n0 += NC) {
    relmat64_kernel<<<dim3(NC * 16), 256, 0, stream>>>(R_word, RelT, n0);
    prefix16_kernel<<<dim3(4, NC), 256, 0, stream>>>(M_f, R_word, PS, n0);
    mqk_kernel<<<dim3(8, NC), 256, 0, stream>>>(M_h, M_l, qwT_h, qwT_l, kwT_h, kwT_l,
                                                MQh, MQl, MKh, MKl, n0);
    stage1band_kernel<<<dim3(16, 8, NC), 256, 0, stream>>>(M_f, RelT, PS, C1r, n0);
    logits_kernel<<<dim3(8, 8, NC), 256, 0, stream>>>(q_bpe, k_bpe, MQh, MQl, MKh, MKl,
                                                      C1r, M_f, R_bpe, L_c, n0);
    softmax_pv_kernel<<<dim3(16, NC), 256, 0, stream>>>(L_c, VTb, AO, n0);
  }

  outproj_kernel<<<dim3(8, 32), 256, 0, stream>>>(AO, Wo, Wo_bf, prep, bo, (float*)d_out);
}

// Round 3
// 627.137 us; speedup vs baseline: 1.2239x; 1.1647x over previous
//
#include <hip/hip_runtime.h>

// RelativeBPEWORDFusionMultiheadAttention on MI355X (gfx950). FP32 in/out.
// Factorization: fused = (MQ)(MK)^T + M·Rel·M^T (content Dekker-bf16, Rel fp16).
// Round 12: counted-vmcnt software pipeline. __syncthreads() drains vmcnt(0)
// (kills any dbuf); replaced in all hot K-loops with the T3/T4 pattern:
//   stage(t+1) -> s_waitcnt vmcnt(N_in_flight) -> raw s_barrier -> MFMA(t) -> raw s_barrier
// so next-tile global_load_lds stay in flight across barriers. logits LDS cut
// 64->32 KB (5 blk/CU). stage1band one-shot K=64 stage. relmat+prefix merged.

#define DEV __device__ __forceinline__
#define GAS(x) ((const __attribute__((address_space(1))) unsigned*)(x))
#define LAS(x) ((__attribute__((address_space(3))) unsigned*)(x))

typedef unsigned short u16;
typedef __attribute__((ext_vector_type(8))) short short8;
typedef __attribute__((ext_vector_type(8))) _Float16 half8;
typedef __attribute__((ext_vector_type(4))) float floatx4;

DEV float bf2f(u16 u) { union { unsigned u; float f; } v; v.u = ((unsigned)u) << 16; return v.f; }
DEV u16 f2bf(float f) {
  union { float f; unsigned u; } v; v.f = f;
  unsigned r = v.u + 0x7FFFu + ((v.u >> 16) & 1u);  // RNE
  return (u16)(r >> 16);
}
DEV u16 f2h_bits(float f) { union { _Float16 h; u16 u; } v; v.h = (_Float16)f; return v.u; }

// counted wait: only the N oldest vector-memory ops may remain outstanding
template <int N> DEV void vmwait() {
  asm volatile("s_waitcnt vmcnt(%0)" ::"n"(N) : "memory");
  __builtin_amdgcn_sched_barrier(0);
}
DEV void barrier_raw() {
  asm volatile("" ::: "memory");
  __builtin_amdgcn_s_barrier();
  asm volatile("" ::: "memory");
}

// ---- LDS tile [128][32] u16, 16B-chunk XOR swizzle (source-side permute) ----
DEV void stage_u16(const u16* g, int ld, u16* lds, int tid) {
#pragma unroll
  for (int p = 0; p < 2; ++p) {
    int o = (p * 256 + tid) * 16;
    int r = o >> 6, c = (o >> 4) & 3, sc = c ^ ((r >> 1) & 3);
    __builtin_amdgcn_global_load_lds(GAS(g + (size_t)r * ld + sc * 8),
                                     LAS((char*)lds + o), 16, 0, 0);
  }
}

DEV void stage_u16_half(const u16* g, int ld, u16* lds, int tid, int p) {
  int o = (p * 256 + tid) * 16;
  int r = o >> 6, c = (o >> 4) & 3, sc = c ^ ((r >> 1) & 3);
  __builtin_amdgcn_global_load_lds(GAS(g + (size_t)(r - p * 64) * ld + sc * 8),
                                   LAS((char*)lds + o), 16, 0, 0);
}

DEV void stage_f32_bf(const float* g, int ld, u16* lds, int tid) {
#pragma unroll
  for (int p = 0; p < 2; ++p) {
    int o = (p * 256 + tid) * 16;
    int r = o >> 6, c = (o >> 4) & 3, sc = c ^ ((r >> 1) & 3);
    const float* src = g + (size_t)r * ld + sc * 8;
    union { short8 s; u16 u[8]; } oh;
#pragma unroll
    for (int j = 0; j < 8; ++j) oh.u[j] = f2bf(src[j]);
    *(short8*)((char*)lds + o) = oh.s;
  }
}

DEV void stage_f32_split(const float* g, int ld, u16* ldsh, u16* ldsl, int tid) {
#pragma unroll
  for (int p = 0; p < 2; ++p) {
    int o = (p * 256 + tid) * 16;
    int r = o >> 6, c = (o >> 4) & 3, sc = c ^ ((r >> 1) & 3);
    const float* src = g + (size_t)r * ld + sc * 8;
    union { short8 s; u16 u[8]; } oh, ol;
#pragma unroll
    for (int j = 0; j < 8; ++j) {
      float f = src[j];
      u16 h = f2bf(f);
      oh.u[j] = h;
      ol.u[j] = f2bf(f - bf2f(h));
    }
    *(short8*)((char*)ldsh + o) = oh.s;
    *(short8*)((char*)ldsl + o) = ol.s;
  }
}

DEV short8 frag_ld(const u16* lds, int row, int quad) {
  int c = quad ^ ((row >> 1) & 3);
  return *(const short8*)(lds + row * 32 + c * 8);
}

DEV void mma_bf16(const u16* As, const u16* Bs, int wr, int wc, int m, int quad, floatx4 acc[4][4]) {
  short8 af[4], bf[4];
#pragma unroll
  for (int t = 0; t < 4; ++t) af[t] = frag_ld(As, wr * 64 + t * 16 + m, quad);
#pragma unroll
  for (int t = 0; t < 4; ++t) bf[t] = frag_ld(Bs, wc * 64 + t * 16 + m, quad);
#pragma unroll
  for (int rt = 0; rt < 4; ++rt)
#pragma unroll
    for (int ct = 0; ct < 4; ++ct)
      acc[rt][ct] = __builtin_amdgcn_mfma_f32_16x16x32_bf16(af[rt], bf[ct], acc[rt][ct], 0, 0, 0);
}

DEV void mma_f16(const u16* As, const u16* Bs, int wr, int wc, int m, int quad, floatx4 acc[4][4]) {
  union { short8 s; half8 h; } af[4], bf[4];
#pragma unroll
  for (int t = 0; t < 4; ++t) af[t].s = frag_ld(As, wr * 64 + t * 16 + m, quad);
#pragma unroll
  for (int t = 0; t < 4; ++t) bf[t].s = frag_ld(Bs, wc * 64 + t * 16 + m, quad);
#pragma unroll
  for (int rt = 0; rt < 4; ++rt)
#pragma unroll
    for (int ct = 0; ct < 4; ++ct)
      acc[rt][ct] = __builtin_amdgcn_mfma_f32_16x16x32_f16(af[rt].h, bf[ct].h, acc[rt][ct], 0, 0, 0);
}

// Dekker 3-pass: hh + hl + lh (bf16 operands, ~2^-16 effective)
DEV void mma_split(const u16* AsH, const u16* AsL, const u16* BsH, const u16* BsL,
                   int wr, int wc, int m, int quad, floatx4 acc[4][4]) {
  short8 ah[4], al[4], bh[4], bl[4];
#pragma unroll
  for (int t = 0; t < 4; ++t) {
    ah[t] = frag_ld(AsH, wr * 64 + t * 16 + m, quad);
    al[t] = frag_ld(AsL, wr * 64 + t * 16 + m, quad);
    bh[t] = frag_ld(BsH, wc * 64 + t * 16 + m, quad);
    bl[t] = frag_ld(BsL, wc * 64 + t * 16 + m, quad);
  }
#pragma unroll
  for (int rt = 0; rt < 4; ++rt)
#pragma unroll
    for (int ct = 0; ct < 4; ++ct) {
      acc[rt][ct] = __builtin_amdgcn_mfma_f32_16x16x32_bf16(ah[rt], bh[ct], acc[rt][ct], 0, 0, 0);
      acc[rt][ct] = __builtin_amdgcn_mfma_f32_16x16x32_bf16(ah[rt], bl[ct], acc[rt][ct], 0, 0, 0);
      acc[rt][ct] = __builtin_amdgcn_mfma_f32_16x16x32_bf16(al[rt], bh[ct], acc[rt][ct], 0, 0, 0);
    }
}

DEV void acc_zero(floatx4 acc[4][4]) {
  floatx4 z = {0.f, 0.f, 0.f, 0.f};
#pragma unroll
  for (int i = 0; i < 4; ++i)
#pragma unroll
    for (int j = 0; j < 4; ++j) acc[i][j] = z;
}

// ---------------- input pre-conversion ----------------
struct CvtB { const float* src[5]; u16* dst[5]; int n8[5]; };
__global__ __launch_bounds__(256) void cvt_bf_kernel(CvtB a) {
  int z = blockIdx.z;
  int i = blockIdx.x * 256 + threadIdx.x;
  if (i >= a.n8[z]) return;
  const float* s = a.src[z] + (size_t)i * 8;
  union { short8 v; u16 u[8]; } o;
#pragma unroll
  for (int j = 0; j < 8; ++j) o.u[j] = f2bf(s[j]);
  *(short8*)(a.dst[z] + (size_t)i * 8) = o.v;
}

struct CvtS { const float* src[3]; u16* dh[3]; u16* dl[3]; int n8[3]; };
__global__ __launch_bounds__(256) void cvt_split_kernel(CvtS a) {
  int z = blockIdx.z;
  int i = blockIdx.x * 256 + threadIdx.x;
  if (i >= a.n8[z]) return;
  const float* s = a.src[z] + (size_t)i * 8;
  union { short8 v; u16 u[8]; } oh, ol;
#pragma unroll
  for (int j = 0; j < 8; ++j) {
    float f = s[j];
    u16 h = f2bf(f);
    oh.u[j] = h;
    ol.u[j] = f2bf(f - bf2f(h));
  }
  *(short8*)(a.dh[z] + (size_t)i * 8) = oh.v;
  *(short8*)(a.dl[z] + (size_t)i * 8) = ol.v;
}

// ---------------- all 5 projections, one launch ----------------
// z: 0=q_bpe(bf16) 1=k_bpe(bf16) 2=V->VT(bf16) 3=q_word(Dekker->transposed h/l)
//    4=k_word(Dekker->transposed h/l)
struct PAll {
  const float* Xf[5]; const float* Wf[5];
  const u16* Xh[5]; const u16* Xl[5]; const u16* Wh[5]; const u16* Wl[5];
  const float* bias[5]; float scale[5];
  u16* dh[5]; u16* dl[5]; int T[5]; int md[5]; int prep;
};

__global__ __launch_bounds__(256) void proj_all_kernel(PAll a) {
  const int z = blockIdx.z;
  const int T = a.T[z];
  if ((int)blockIdx.y >= (T >> 5)) return;
  __shared__ __align__(16) u16 LB[8][4096];  // 64 KB pool: pipelined K-loop, then transpose
  const int tid = threadIdx.x;
  const int lane = tid & 63, wv = tid >> 6, wr = wv >> 1, wc = wv & 1;
  const int m = lane & 15, quad = lane >> 4;
  const int md = a.md[z], prep = a.prep;
  const int bx = blockIdx.x, by = blockIdx.y;
  const size_t arow = (size_t)by * 128 * 1024;
  const size_t brow = (size_t)bx * 128 * 1024;
  floatx4 acc[4][4];
  acc_zero(acc);
  if (prep) {
    const u16* Xh = a.Xh[z]; const u16* Xl = a.Xl[z];
    const u16* Wh = a.Wh[z]; const u16* Wl = a.Wl[z];
    if (md == 2) {
      // counted-vmcnt pipeline, sets of 4 tiles [Ah,Bh,Al,Bl]
      stage_u16(Xh + arow, 1024, LB[0], tid);
      stage_u16(Wh + brow, 1024, LB[1], tid);
      stage_u16(Xl + arow, 1024, LB[2], tid);
      stage_u16(Wl + brow, 1024, LB[3], tid);
      for (int k0 = 0; k0 < 1024; k0 += 32) {
        int o = ((k0 >> 5) & 1) * 4;
        if (k0 + 32 < 1024) {
          int no = 4 - o;
          stage_u16(Xh + arow + k0 + 32, 1024, LB[no], tid);
          stage_u16(Wh + brow + k0 + 32, 1024, LB[no + 1], tid);
          stage_u16(Xl + arow + k0 + 32, 1024, LB[no + 2], tid);
          stage_u16(Wl + brow + k0 + 32, 1024, LB[no + 3], tid);
          vmwait<8>();
        } else vmwait<0>();
        barrier_raw();
        mma_split(LB[o], LB[o + 2], LB[o + 1], LB[o + 3], wr, wc, m, quad, acc);
        barrier_raw();
      }
    } else {
      stage_u16(Xh + arow, 1024, LB[0], tid);
      stage_u16(Wh + brow, 1024, LB[1], tid);
      for (int k0 = 0; k0 < 1024; k0 += 32) {
        int o = ((k0 >> 5) & 1) * 2;
        if (k0 + 32 < 1024) {
          int no = 2 - o;
          stage_u16(Xh + arow + k0 + 32, 1024, LB[no], tid);
          stage_u16(Wh + brow + k0 + 32, 1024, LB[no + 1], tid);
          vmwait<4>();
        } else vmwait<0>();
        barrier_raw();
        mma_bf16(LB[o], LB[o + 1], wr, wc, m, quad, acc);
        barrier_raw();
      }
    }
  } else {
    for (int k0 = 0; k0 < 1024; k0 += 32) {
      __syncthreads();
      if (md == 2) {
        stage_f32_split(a.Xf[z] + arow + k0, 1024, LB[0], LB[4], tid);
        stage_f32_split(a.Wf[z] + brow + k0, 1024, LB[2], LB[6], tid);
      } else {
        stage_f32_bf(a.Xf[z] + arow + k0, 1024, LB[0], tid);
        stage_f32_bf(a.Wf[z] + brow + k0, 1024, LB[2], tid);
      }
      __syncthreads();
      if (md == 2) mma_split(LB[0], LB[4], LB[2], LB[6], wr, wc, m, quad, acc);
      else         mma_bf16(LB[0], LB[2], wr, wc, m, quad, acc);
    }
    __syncthreads();
  }
  const float scale = a.scale[z];
  const float* bias = a.bias[z];
  u16* dh = a.dh[z];
  u16* dl = a.dl[z];
  const int row0l = wr * 64 + quad * 4;
  const int col0l = wc * 64 + m;
  if (md == 0) {
#pragma unroll
    for (int rt = 0; rt < 4; ++rt)
#pragma unroll
      for (int ct = 0; ct < 4; ++ct) {
        int col = bx * 128 + col0l + ct * 16;
        float bi = bias[col];
        int h = col >> 6, d = col & 63;
#pragma unroll
        for (int rg = 0; rg < 4; ++rg) {
          int row = by * 128 + row0l + rt * 16 + rg;
          int t = row >> 2, bb = row & 3, n = bb * 16 + h;
          float val = (acc[rt][ct][rg] + bi) * scale;
          dh[((size_t)n * T + t) * 64 + d] = f2bf(val);
        }
      }
  } else if (md == 1) {
    // transpose via LDS, emit 64B-contiguous stores to VT[n][d][t]
    u16* TB = (u16*)LB;  // [128 cols][stride 130 rows] u16 (33280 B)
    __syncthreads();
#pragma unroll
    for (int rt = 0; rt < 4; ++rt)
#pragma unroll
      for (int ct = 0; ct < 4; ++ct) {
        int cl = col0l + ct * 16;
        float bi = bias[bx * 128 + cl];
#pragma unroll
        for (int rg = 0; rg < 4; ++rg) {
          int rl = row0l + rt * 16 + rg;
          TB[(size_t)cl * 130 + rl] = f2bf((acc[rt][ct][rg] + bi) * scale);
        }
      }
    __syncthreads();
    for (int task = tid; task < 512; task += 256) {
      int c = task & 127, bb = task >> 7;
      int colg = bx * 128 + c, h = colg >> 6, d = colg & 63;
      size_t base = (((size_t)(bb * 16 + h)) * 64 + d) * 1024 + (size_t)by * 32;
#pragma unroll
      for (int g = 0; g < 4; ++g) {
        union { short8 v; u16 u[8]; } o;
#pragma unroll
        for (int j = 0; j < 8; ++j) o.u[j] = TB[(size_t)c * 130 + bb + 4 * (g * 8 + j)];
        *(short8*)(dh + base + g * 8) = o.v;
      }
    }
  } else {
    // md==2: Dekker h/l transposed stores, two col-half passes
    u16* TBh = (u16*)LB;          // [64][130]
    u16* TBl = TBh + 64 * 130;
    for (int pass = 0; pass < 2; ++pass) {
      __syncthreads();
      if (wc == pass) {
#pragma unroll
        for (int rt = 0; rt < 4; ++rt)
#pragma unroll
          for (int ct = 0; ct < 4; ++ct) {
            int cl = ct * 16 + m;
            float bi = bias[bx * 128 + pass * 64 + cl];
#pragma unroll
            for (int rg = 0; rg < 4; ++rg) {
              int rl = row0l + rt * 16 + rg;
              float val = (acc[rt][ct][rg] + bi) * scale;
              u16 hh = f2bf(val);
              TBh[(size_t)cl * 130 + rl] = hh;
              TBl[(size_t)cl * 130 + rl] = f2bf(val - bf2f(hh));
            }
          }
      }
      __syncthreads();
      int c2 = tid & 63, bb = tid >> 6;
      int colg = bx * 128 + pass * 64 + c2, h = colg >> 6, d = colg & 63;
      size_t base = (((size_t)(bb * 16 + h)) * 64 + d) * 512 + (size_t)by * 32;
#pragma unroll
      for (int g = 0; g < 4; ++g) {
        union { short8 v; u16 u[8]; } oh, ol;
#pragma unroll
        for (int j = 0; j < 8; ++j) {
          oh.u[j] = TBh[(size_t)c2 * 130 + bb + 4 * (g * 8 + j)];
          ol.u[j] = TBl[(size_t)c2 * 130 + bb + 4 * (g * 8 + j)];
        }
        *(short8*)(dh + base + g * 8) = oh.v;
        *(short8*)(dl + base + g * 8) = ol.v;
      }
    }
  }
}

// ---------------- M -> Mh,Ml (bf16 Dekker) + Mf (fp16) ----------------
__global__ __launch_bounds__(256) void msplit_kernel(const float* __restrict__ M,
                                                     u16* __restrict__ Mh, u16* __restrict__ Ml,
                                                     u16* __restrict__ Mf) {
  int i = blockIdx.x * 256 + threadIdx.x;
  float f = M[i];
  u16 h = f2bf(f);
  Mh[i] = h;
  Ml[i] = f2bf(f - bf2f(h));
  Mf[i] = f2h_bits(f);
}

// ---------------- rel tables ----------------
__global__ __launch_bounds__(256) void rel_bpe_kernel(const u16* __restrict__ q,
                                                      const float* __restrict__ relk,
                                                      float* __restrict__ R) {
  int nt = blockIdx.x * 256 + threadIdx.x;
  float qv[64];
#pragma unroll
  for (int c = 0; c < 8; ++c) {
    union { short8 s; u16 u[8]; } uh; uh.s = *(const short8*)(q + (size_t)nt * 64 + c * 8);
#pragma unroll
    for (int j = 0; j < 8; ++j) qv[c * 8 + j] = bf2f(uh.u[j]);
  }
  for (int r = 0; r < 33; ++r) {
    const float* krow = relk + r * 64;
    float s = 0.f;
#pragma unroll
    for (int d = 0; d < 64; ++d) s += qv[d] * krow[d];
    R[(size_t)nt * 33 + r] = s;
  }
}

__global__ __launch_bounds__(256) void rel_word_kernel(const u16* __restrict__ qh, const u16* __restrict__ ql,
                                                       const float* __restrict__ relk,
                                                       float* __restrict__ R) {
  int nt = blockIdx.x * 256 + threadIdx.x;
  int n = nt >> 9, w = nt & 511;
  float qv[64];
#pragma unroll
  for (int d = 0; d < 64; ++d) {
    size_t idx = ((size_t)n * 64 + d) * 512 + w;
    qv[d] = bf2f(qh[idx]) + bf2f(ql[idx]);
  }
  for (int r = 0; r < 33; ++r) {
    const float* krow = relk + r * 64;
    float s = 0.f;
#pragma unroll
    for (int d = 0; d < 64; ++d) s += qv[d] * krow[d];
    R[(size_t)nt * 33 + r] = s;
  }
}

// ---- merged RelT build + coarse prefixes (one launch per chunk) -------------
// blocks [0, NC*16): RelT[nl][t][s][w] windowed fp16 tiles
// blocks [NC*16, NC*20): PS prefix/suffix scalars
__global__ __launch_bounds__(256) void relprefix_kernel(const float* __restrict__ Rw,
                                                        const u16* __restrict__ Mf,
                                                        u16* __restrict__ RT,
                                                        float* __restrict__ PS,
                                                        int NCx, int n0) {
  const int bx = blockIdx.x;
  if (bx < NCx * 16) {
    int i = bx * 256 + threadIdx.x;
    int w8 = i & 7, s = (i >> 3) & 31, t = (i >> 8) & 15, nl = i >> 12;
    int n = n0 + nl;
    int w0 = (t == 0) ? 0 : (t == 15 ? 448 : 32 * t - 16);
    int sg = t * 32 + s;
    const float* R = Rw + (size_t)n * 512 * 33;
    union { short8 v; u16 u[8]; } o;
#pragma unroll
    for (int j = 0; j < 8; ++j) {
      int w = w0 + w8 * 8 + j;
      int d = sg - w; d = d < -16 ? -16 : (d > 16 ? 16 : d);
      o.u[j] = f2h_bits(R[(size_t)w * 33 + d + 16]);
    }
    *(short8*)(RT + (size_t)i * 8) = o.v;
  } else {
    const int px = bx - NCx * 16;
    const int nl = px >> 2, n = n0 + nl, b = n >> 4;
    const int q = (px & 3) * 256 + threadIdx.x;
    const u16* mrow = Mf + ((size_t)b * 1024 + q) * 512;
    const float* R = Rw + (size_t)n * 512 * 33;
    float* ps = PS + ((size_t)nl * 1024 + q) * 66;
    float blkA[32], blkB[32];
#pragma unroll
    for (int t = 0; t < 32; ++t) {
      float a = 0.f, bb = 0.f;
#pragma unroll
      for (int c = 0; c < 2; ++c) {
        union { short8 s; _Float16 h[8]; } u;
        u.s = *(const short8*)(mrow + t * 16 + c * 8);
#pragma unroll
        for (int j = 0; j < 8; ++j) {
          int w = t * 16 + c * 8 + j;
          float mv = (float)u.h[j];
          a += mv * R[(size_t)w * 33 + 32];
          bb += mv * R[(size_t)w * 33];
        }
      }
      blkA[t] = a; blkB[t] = bb;
    }
    float run = 0.f;
#pragma unroll
    for (int i = 0; i < 33; ++i) { ps[i] = run; if (i < 32) run += blkA[i]; }
    float tot = 0.f;
#pragma unroll
    for (int i = 0; i < 32; ++i) tot += blkB[i];
    run = tot;
#pragma unroll
    for (int i = 0; i < 33; ++i) { ps[33 + i] = run; if (i < 32) run -= blkB[i]; }
  }
}

// ---- stage1 band: C1r[nl][q][s] = K=64 windowed MFMA + alpha[q] + beta[q] ----
// One-shot stage of the whole K=64 (A 16KB + B 4KB, uniform), single barrier.
__global__ __launch_bounds__(256) void stage1band_kernel(const u16* __restrict__ Mf,
                                                         const u16* __restrict__ RT,
                                                         const float* __restrict__ PS,
                                                         u16* __restrict__ C1r, int n0) {
  __shared__ __align__(16) u16 As[2][4096], Bs[2][1024];
  const int tid = threadIdx.x, t = blockIdx.x, nl = blockIdx.z, n = n0 + nl, b = n >> 4;
  const int lane = tid & 63, wv = tid >> 6;
  const int m = lane & 15, quad = lane >> 4;
  const int w0 = (t == 0) ? 0 : (t == 15 ? 448 : 32 * t - 16);
  const size_t ma = ((size_t)b * 1024 + blockIdx.y * 128) * 512 + w0;
  const u16* rt = RT + ((size_t)nl * 16 + t) * 2048;
  stage_u16(Mf + ma, 512, As[0], tid);
  stage_u16(Mf + ma + 32, 512, As[1], tid);
  {
    int half = tid >> 7, tt = tid & 127, o = tt * 16;
    int r = o >> 6, c = (o >> 4) & 3, sc = c ^ ((r >> 1) & 3);
    __builtin_amdgcn_global_load_lds(GAS(rt + half * 32 + (size_t)r * 64 + sc * 8),
                                     LAS((char*)Bs[half] + o), 16, 0, 0);
  }
  floatx4 acc[2][2];
  floatx4 z = {0.f, 0.f, 0.f, 0.f};
  acc[0][0] = z; acc[0][1] = z; acc[1][0] = z; acc[1][1] = z;
  __syncthreads();
#pragma unroll
  for (int ks = 0; ks < 2; ++ks) {
    union { short8 s; half8 h; } af[2], bf[2];
#pragma unroll
    for (int i = 0; i < 2; ++i) af[i].s = frag_ld(As[ks], wv * 32 + i * 16 + m, quad);
#pragma unroll
    for (int i = 0; i < 2; ++i) bf[i].s = frag_ld(Bs[ks], i * 16 + m, quad);
#pragma unroll
    for (int i = 0; i < 2; ++i)
#pragma unroll
      for (int j = 0; j < 2; ++j)
        acc[i][j] = __builtin_amdgcn_mfma_f32_16x16x32_f16(af[i].h, bf[j].h, acc[i][j], 0, 0, 0);
  }
  const int ia = w0 >> 4, ib = (w0 + 64) >> 4;
  const float* ps = PS + ((size_t)nl * 1024 + blockIdx.y * 128) * 66;
#pragma unroll
  for (int i = 0; i < 2; ++i)
#pragma unroll
    for (int rg = 0; rg < 4; ++rg) {
      int row = wv * 32 + i * 16 + quad * 4 + rg;
      float ab = ps[(size_t)row * 66 + ia] + ps[(size_t)row * 66 + 33 + ib];
      int q = blockIdx.y * 128 + row;
#pragma unroll
      for (int j = 0; j < 2; ++j) {
        int s = t * 32 + j * 16 + m;
        C1r[((size_t)nl * 1024 + q) * 512 + s] = f2h_bits(acc[i][j][rg] + ab);
      }
    }
}

// ---------------- MQ/MK: [1024,64] = M[1024,512] x {Q,K}^T, Dekker 3-pass ------
// Counted-vmcnt pipeline; outputs pre-split bf16 h/l so logits stages async.
__global__ __launch_bounds__(256) void mqk_kernel(const u16* __restrict__ Mh, const u16* __restrict__ Ml,
                                                  const u16* __restrict__ qwTh, const u16* __restrict__ qwTl,
                                                  const u16* __restrict__ kwTh, const u16* __restrict__ kwTl,
                                                  u16* __restrict__ MQh, u16* __restrict__ MQl,
                                                  u16* __restrict__ MKh, u16* __restrict__ MKl, int n0) {
  __shared__ __align__(16) u16 LB[8][4096];
  const int tid = threadIdx.x, nl = blockIdx.y, n = n0 + nl, b = n >> 4;
  const int lane = tid & 63, wv = tid >> 6, wr = wv >> 1, wc = wv & 1;
  const int m = lane & 15, quad = lane >> 4;
  const size_t ma = ((size_t)b * 1024 + blockIdx.x * 128) * 512;
  const u16* Qh = qwTh + (size_t)n * 32768;
  const u16* Ql = qwTl + (size_t)n * 32768;
  const u16* Kh = kwTh + (size_t)n * 32768;
  const u16* Kl = kwTl + (size_t)n * 32768;
  floatx4 acc[4][4];
  acc_zero(acc);
  auto stage_set = [&](int o, int k) {
    stage_u16(Mh + ma + k, 512, LB[o], tid);
    stage_u16(Ml + ma + k, 512, LB[o + 1], tid);
    stage_u16_half(Qh + k, 512, LB[o + 2], tid, 0);
    stage_u16_half(Kh + k, 512, LB[o + 2], tid, 1);
    stage_u16_half(Ql + k, 512, LB[o + 3], tid, 0);
    stage_u16_half(Kl + k, 512, LB[o + 3], tid, 1);
  };
  stage_set(0, 0);
  for (int k0 = 0; k0 < 512; k0 += 32) {
    int o = ((k0 >> 5) & 1) * 4;
    if (k0 + 32 < 512) {
      stage_set(4 - o, k0 + 32);
      vmwait<8>();
    } else vmwait<0>();
    barrier_raw();
    mma_split(LB[o], LB[o + 1], LB[o + 2], LB[o + 3], wr, wc, m, quad, acc);
    barrier_raw();
  }
  u16* dsth = wc ? MKh : MQh;
  u16* dstl = wc ? MKl : MQl;
  const int row0 = blockIdx.x * 128 + wr * 64 + quad * 4;
#pragma unroll
  for (int rt = 0; rt < 4; ++rt)
#pragma unroll
    for (int ct = 0; ct < 4; ++ct) {
      int d = (ct * 16 + m) & 63;
#pragma unroll
      for (int rg = 0; rg < 4; ++rg) {
        int row = row0 + rt * 16 + rg;
        size_t idx = ((size_t)nl * 1024 + row) * 64 + d;
        float val = acc[rt][ct][rg];
        u16 hh = f2bf(val);
        dsth[idx] = hh;
        dstl[idx] = f2bf(val - bf2f(hh));
      }
    }
}

// ------ logits: qb.kb (bf16,K64) + MQ.MK^T (Dekker,K64) + C1r.Mf^T (fp16,K512) + rel --
// L stored fp16. x = q-tile (XCD L2 locality). 32 KB LDS; K512 loop uses the
// counted-vmcnt 2-barrier pipeline.
__global__ __launch_bounds__(256) void logits_kernel(const u16* __restrict__ qb, const u16* __restrict__ kb,
                                                     const u16* __restrict__ MQh, const u16* __restrict__ MQl,
                                                     const u16* __restrict__ MKh, const u16* __restrict__ MKl,
                                                     const u16* __restrict__ C1r, const u16* __restrict__ Mf,
                                                     const float* __restrict__ Rb, u16* __restrict__ L,
                                                     int n0) {
  __shared__ __align__(16) u16 LB[4][4096];
  const int tid = threadIdx.x, nl = blockIdx.z, n = n0 + nl, b = n >> 4;
  const int bq = blockIdx.x, bk = blockIdx.y;   // x = q for XCD L2 locality
  const int lane = tid & 63, wv = tid >> 6, wr = wv >> 1, wc = wv & 1;
  const int m = lane & 15, quad = lane >> 4;
  const size_t qa = ((size_t)n * 1024 + bq * 128) * 64;
  const size_t ka = ((size_t)n * 1024 + bk * 128) * 64;
  const size_t mqa = ((size_t)nl * 1024 + bq * 128) * 64;
  const size_t mka = ((size_t)nl * 1024 + bk * 128) * 64;
  const size_t ca = ((size_t)nl * 1024 + bq * 128) * 512;
  const size_t ma = ((size_t)b * 1024 + bk * 128) * 512;
  floatx4 acc[4][4];
  acc_zero(acc);
  // loop1: content QK^T bpe (bf16, K=64)
  stage_u16(qb + qa, 64, LB[0], tid);
  stage_u16(kb + ka, 64, LB[1], tid);
  __syncthreads();
  stage_u16(qb + qa + 32, 64, LB[2], tid);
  stage_u16(kb + ka + 32, 64, LB[3], tid);
  mma_bf16(LB[0], LB[1], wr, wc, m, quad, acc);
  __syncthreads();
  mma_bf16(LB[2], LB[3], wr, wc, m, quad, acc);
  __syncthreads();
  // loop2: (MQ)(MK)^T Dekker, K=64, two 4-tile steps
#pragma unroll
  for (int k0 = 0; k0 < 64; k0 += 32) {
    stage_u16(MQh + mqa + k0, 64, LB[0], tid);
    stage_u16(MQl + mqa + k0, 64, LB[1], tid);
    stage_u16(MKh + mka + k0, 64, LB[2], tid);
    stage_u16(MKl + mka + k0, 64, LB[3], tid);
    __syncthreads();
    mma_split(LB[0], LB[1], LB[2], LB[3], wr, wc, m, quad, acc);
    __syncthreads();
  }
  // loop3: M Rel M^T part 2: C1r @ Mf^T (fp16, K=512) — counted pipeline
  stage_u16(C1r + ca, 512, LB[0], tid);
  stage_u16(Mf + ma, 512, LB[1], tid);
  for (int k0 = 0; k0 < 512; k0 += 32) {
    int o = ((k0 >> 5) & 1) * 2;
    if (k0 + 32 < 512) {
      int no = 2 - o;
      stage_u16(C1r + ca + k0 + 32, 512, LB[no], tid);
      stage_u16(Mf + ma + k0 + 32, 512, LB[no + 1], tid);
      vmwait<4>();
    } else vmwait<0>();
    barrier_raw();
    mma_f16(LB[o], LB[o + 1], wr, wc, m, quad, acc);
    barrier_raw();
  }
  const int q0 = bq * 128 + wr * 64 + quad * 4;
  const int k0c = bk * 128 + wc * 64 + m;
#pragma unroll
  for (int rt = 0; rt < 4; ++rt)
#pragma unroll
    for (int ct = 0; ct < 4; ++ct) {
      int kc = k0c + ct * 16;
#pragma unroll
      for (int rg = 0; rg < 4; ++rg) {
        int q = q0 + rt * 16 + rg;
        int id = kc - q; id = id < -16 ? -16 : (id > 16 ? 16 : id); id += 16;
        float val = acc[rt][ct][rg] + Rb[((size_t)n * 1024 + q) * 33 + id];
        L[((size_t)nl * 1024 + q) * 1024 + kc] = f2h_bits(val);
      }
    }
}

// ---------------- softmax + PV (online; fp16 logits in A-frag layout) ----------
__global__ __launch_bounds__(256) void softmax_pv_kernel(const u16* __restrict__ L,
                                                         const u16* __restrict__ VT,
                                                         u16* __restrict__ AO, int n0) {
  __shared__ __align__(16) u16 Vs[2][4][2048];
  const int tid = threadIdx.x, lane = tid & 63, wv = tid >> 6;
  const int m = lane & 15, quad = lane >> 4;
  const int nl = blockIdx.y, n = n0 + nl, qt = blockIdx.x;
  const int qrow = qt * 64 + wv * 16 + m;
  const u16* Lrow = L + ((size_t)nl * 1024 + qrow) * 1024;
  const u16* Vbase = VT + (size_t)n * 64 * 1024;
  float mi = -1e30f, li = 0.f;
  floatx4 O[4];
  floatx4 z = {0.f, 0.f, 0.f, 0.f};
#pragma unroll
  for (int dt = 0; dt < 4; ++dt) O[dt] = z;

  auto stageV = [&](int kt, int buf) {
#pragma unroll
    for (int ct = 0; ct < 4; ++ct) {
      int o = tid * 16;
      int r = o >> 6, c = (o >> 4) & 3, sc = c ^ ((r >> 1) & 3);
      __builtin_amdgcn_global_load_lds(GAS(Vbase + (size_t)r * 1024 + kt * 128 + ct * 32 + sc * 8),
                                       LAS((char*)Vs[buf][ct] + o), 16, 0, 0);
    }
  };
  stageV(0, 0);
  __syncthreads();

  for (int kt = 0; kt < 8; ++kt) {
    int cur = kt & 1;
    if (kt + 1 < 8) stageV(kt + 1, cur ^ 1);

    float vals[4][8];
#pragma unroll
    for (int ct = 0; ct < 4; ++ct) {
      union { short8 s; _Float16 h[8]; } u;
      u.s = *(const short8*)(Lrow + kt * 128 + ct * 32 + quad * 8);
#pragma unroll
      for (int j = 0; j < 8; ++j) vals[ct][j] = (float)u.h[j];
    }
    float tmax = vals[0][0];
#pragma unroll
    for (int ct = 0; ct < 4; ++ct)
#pragma unroll
      for (int j = 0; j < 8; ++j) tmax = fmaxf(tmax, vals[ct][j]);
    tmax = fmaxf(tmax, __shfl_xor(tmax, 16));
    tmax = fmaxf(tmax, __shfl_xor(tmax, 32));
    float mnew = fmaxf(mi, tmax);
    float alpha = __expf(mi - mnew);
    float pv[4][8];
    float tsum = 0.f;
#pragma unroll
    for (int ct = 0; ct < 4; ++ct)
#pragma unroll
      for (int j = 0; j < 8; ++j) { pv[ct][j] = __expf(vals[ct][j] - mnew); tsum += pv[ct][j]; }
    tsum += __shfl_xor(tsum, 16);
    tsum += __shfl_xor(tsum, 32);
    li = li * alpha + tsum;
    mi = mnew;

    float ar[4];
#pragma unroll
    for (int rg = 0; rg < 4; ++rg) ar[rg] = __shfl(alpha, quad * 4 + rg);
#pragma unroll
    for (int dt = 0; dt < 4; ++dt)
#pragma unroll
      for (int rg = 0; rg < 4; ++rg) O[dt][rg] *= ar[rg];

    short8 pf[4];
#pragma unroll
    for (int ct = 0; ct < 4; ++ct) {
      union { short8 s; u16 us[8]; } up;
#pragma unroll
      for (int j = 0; j < 8; ++j) up.us[j] = f2bf(pv[ct][j]);
      pf[ct] = up.s;
    }
#pragma unroll
    for (int ct = 0; ct < 4; ++ct)
#pragma unroll
      for (int dt = 0; dt < 4; ++dt) {
        short8 vf = frag_ld(Vs[cur][ct], dt * 16 + m, quad);
        O[dt] = __builtin_amdgcn_mfma_f32_16x16x32_bf16(pf[ct], vf, O[dt], 0, 0, 0);
      }
    __syncthreads();
  }

  float linv = 1.f / li;
  float lr[4];
#pragma unroll
  for (int rg = 0; rg < 4; ++rg) lr[rg] = __shfl(linv, quad * 4 + rg);
  const int b = n >> 4, h = n & 15;
#pragma unroll
  for (int dt = 0; dt < 4; ++dt)
#pragma unroll
    for (int rg = 0; rg < 4; ++rg) {
      int q = qt * 64 + wv * 16 + quad * 4 + rg;
      float ov = O[dt][rg] * lr[rg];
      AO[((size_t)q * 4 + b) * 1024 + h * 64 + dt * 16 + m] = f2bf(ov);
    }
}

// ---------------- output projection: out = AO @ Wo^T + bo  (fp32 out) ----------
__global__ __launch_bounds__(256) void outproj_kernel(const u16* __restrict__ AO, const float* __restrict__ Wo,
                                                      const u16* __restrict__ Wob, int prep,
                                                      const float* __restrict__ bo, float* __restrict__ out) {
  __shared__ __align__(16) u16 LB[4][4096];
  const int tid = threadIdx.x;
  const int lane = tid & 63, wv = tid >> 6, wr = wv >> 1, wc = wv & 1;
  const int m = lane & 15, quad = lane >> 4;
  const u16* A = AO + (size_t)blockIdx.y * 128 * 1024;
  const size_t brow = (size_t)blockIdx.x * 128 * 1024;
  floatx4 acc[4][4];
  acc_zero(acc);
  if (prep) {
    stage_u16(A, 1024, LB[0], tid);
    stage_u16(Wob + brow, 1024, LB[1], tid);
    for (int k0 = 0; k0 < 1024; k0 += 32) {
      int o = ((k0 >> 5) & 1) * 2;
      if (k0 + 32 < 1024) {
        int no = 2 - o;
        stage_u16(A + k0 + 32, 1024, LB[no], tid);
        stage_u16(Wob + brow + k0 + 32, 1024, LB[no + 1], tid);
        vmwait<4>();
      } else vmwait<0>();
      barrier_raw();
      mma_bf16(LB[o], LB[o + 1], wr, wc, m, quad, acc);
      barrier_raw();
    }
  } else {
    for (int k0 = 0; k0 < 1024; k0 += 32) {
      __syncthreads();
      stage_u16(A + k0, 1024, LB[0], tid);
      stage_f32_bf(Wo + brow + k0, 1024, LB[2], tid);
      __syncthreads();
      mma_bf16(LB[0], LB[2], wr, wc, m, quad, acc);
    }
  }
  const int r0 = blockIdx.y * 128 + wr * 64 + quad * 4;
  const int c0 = blockIdx.x * 128 + wc * 64 + m;
#pragma unroll
  for (int rt = 0; rt < 4; ++rt)
#pragma unroll
    for (int ct = 0; ct < 4; ++ct) {
      int col = c0 + ct * 16;
      float bi = bo[col];
#pragma unroll
      for (int rg = 0; rg < 4; ++rg) {
        int row = r0 + rt * 16 + rg;
        out[(size_t)row * 1024 + col] = acc[rt][ct][rg] + bi;
      }
    }
}

extern "C" void kernel_launch(void* const* d_in, const int* in_sizes, int n_in,
                              void* d_out, int out_size, void* d_ws, size_t ws_size,
                              hipStream_t stream) {
  const float* query_bpe = (const float*)d_in[0];
  const float* query_word = (const float*)d_in[1];
  const float* mapping = (const float*)d_in[2];
  const float* Wq_bpe = (const float*)d_in[3];
  const float* bq_bpe = (const float*)d_in[4];
  const float* Wk_bpe = (const float*)d_in[5];
  const float* bk_bpe = (const float*)d_in[6];
  const float* Wq_word = (const float*)d_in[7];
  const float* bq_word = (const float*)d_in[8];
  const float* Wk_word = (const float*)d_in[9];
  const float* bk_word = (const float*)d_in[10];
  const float* Wv = (const float*)d_in[11];
  const float* bv = (const float*)d_in[12];
  const float* Wo = (const float*)d_in[13];
  const float* bo = (const float*)d_in[14];
  const float* relk = (const float*)d_in[15];

  char* ws = (char*)d_ws;
  size_t off = 0;
  u16* q_bpe = (u16*)(ws + off); off += 8388608;   // [64][1024][64] bf16
  u16* k_bpe = (u16*)(ws + off); off += 8388608;
  u16* VTb   = (u16*)(ws + off); off += 8388608;   // [64][64][1024] bf16
  u16* qwT_h = (u16*)(ws + off); off += 4194304;   // [64][64][512] bf16 hi (transposed)
  u16* qwT_l = (u16*)(ws + off); off += 4194304;
  u16* kwT_h = (u16*)(ws + off); off += 4194304;
  u16* kwT_l = (u16*)(ws + off); off += 4194304;
  u16* M_h   = (u16*)(ws + off); off += 4194304;   // [4][1024][512] bf16
  u16* M_l   = (u16*)(ws + off); off += 4194304;
  u16* M_f   = (u16*)(ws + off); off += 4194304;   // fp16
  float* R_word = (float*)(ws + off); off += 4325376;  // [64][512][33]
  float* R_bpe  = (float*)(ws + off); off += 8650752;  // [64][1024][33]
  u16* AO    = (u16*)(ws + off); off += 8388608;   // [4096][1024] bf16
  u16* Wo_bf = (u16*)(ws + off); off += 2097152;   // Wo bf16 (read at the very end)
  const size_t fixed_end = off;                    // ~79.6 MB

  // Union region: transient prep buffers (30 MB, dead after proj_all) overlap
  // the per-chunk loop buffers. Stream serialization makes this safe.
  const size_t avail = (ws_size > fixed_end) ? ws_size - fixed_end : 0;
  const int prep = avail >= 31457280 ? 1 : 0;
  // per-nl: RelT 64K + PS 264K + C1r 1M + L 2M + MQ/MK h+l 4x128K
  const size_t per_nc = 4005888;
  int NC = 1;
  for (int c = 64; c >= 1; c >>= 1) {
    if ((size_t)c * per_nc <= avail) { NC = c; break; }
  }
  char* vb = ws + fixed_end;
  // loop buffers
  u16* RelT  = (u16*)(vb);                                  // NC*65536
  float* PS  = (float*)(vb + (size_t)NC * 65536);           // NC*270336
  u16* C1r   = (u16*)(vb + (size_t)NC * 335872);            // NC*1048576
  u16* L_c   = (u16*)(vb + (size_t)NC * 1384448);           // NC*2097152
  u16* MQh   = (u16*)(vb + (size_t)NC * 3481600);           // NC*131072
  u16* MQl   = (u16*)(vb + (size_t)NC * 3612672);
  u16* MKh   = (u16*)(vb + (size_t)NC * 3743744);
  u16* MKl   = (u16*)(vb + (size_t)NC * 3874816);           // end NC*4005888
  // prep buffers (same bytes, earlier in time)
  u16* Xb    = (u16*)(vb);               // 8 MB  query_bpe bf16
  u16* Wqb   = (u16*)(vb + 8388608);     // 2 MB
  u16* Wkb   = (u16*)(vb + 10485760);
  u16* Wvb   = (u16*)(vb + 12582912);
  u16* Xw_h  = (u16*)(vb + 14680064);    // 4 MB
  u16* Xw_l  = (u16*)(vb + 18874368);
  u16* Wqw_h = (u16*)(vb + 23068672);    // 2 MB
  u16* Wqw_l = (u16*)(vb + 25165824);
  u16* Wkw_h = (u16*)(vb + 27262976);
  u16* Wkw_l = (u16*)(vb + 29360128);    // end 30 MB

  if (prep) {
    CvtB cb = {};
    cb.src[0] = query_bpe; cb.dst[0] = Xb;    cb.n8[0] = 524288;
    cb.src[1] = Wq_bpe;    cb.dst[1] = Wqb;   cb.n8[1] = 131072;
    cb.src[2] = Wk_bpe;    cb.dst[2] = Wkb;   cb.n8[2] = 131072;
    cb.src[3] = Wv;        cb.dst[3] = Wvb;   cb.n8[3] = 131072;
    cb.src[4] = Wo;        cb.dst[4] = Wo_bf; cb.n8[4] = 131072;
    cvt_bf_kernel<<<dim3(2048, 1, 5), 256, 0, stream>>>(cb);
    CvtS cs = {};
    cs.src[0] = query_word; cs.dh[0] = Xw_h;  cs.dl[0] = Xw_l;  cs.n8[0] = 262144;
    cs.src[1] = Wq_word;    cs.dh[1] = Wqw_h; cs.dl[1] = Wqw_l; cs.n8[1] = 131072;
    cs.src[2] = Wk_word;    cs.dh[2] = Wkw_h; cs.dl[2] = Wkw_l; cs.n8[2] = 131072;
    cvt_split_kernel<<<dim3(1024, 1, 3), 256, 0, stream>>>(cs);
  }

  PAll pa = {};
  pa.prep = prep;
  pa.Xf[0] = query_bpe;  pa.Wf[0] = Wq_bpe;  pa.Xh[0] = Xb;   pa.Wh[0] = Wqb;
  pa.bias[0] = bq_bpe;  pa.scale[0] = 0.125f; pa.dh[0] = q_bpe; pa.T[0] = 1024; pa.md[0] = 0;
  pa.Xf[1] = query_bpe;  pa.Wf[1] = Wk_bpe;  pa.Xh[1] = Xb;   pa.Wh[1] = Wkb;
  pa.bias[1] = bk_bpe;  pa.scale[1] = 1.0f;   pa.dh[1] = k_bpe; pa.T[1] = 1024; pa.md[1] = 0;
  pa.Xf[2] = query_bpe;  pa.Wf[2] = Wv;      pa.Xh[2] = Xb;   pa.Wh[2] = Wvb;
  pa.bias[2] = bv;      pa.scale[2] = 1.0f;   pa.dh[2] = VTb;   pa.T[2] = 1024; pa.md[2] = 1;
  pa.Xf[3] = query_word; pa.Wf[3] = Wq_word; pa.Xh[3] = Xw_h; pa.Xl[3] = Xw_l;
  pa.Wh[3] = Wqw_h; pa.Wl[3] = Wqw_l;
  pa.bias[3] = bq_word; pa.scale[3] = 0.125f; pa.dh[3] = qwT_h; pa.dl[3] = qwT_l; pa.T[3] = 512; pa.md[3] = 2;
  pa.Xf[4] = query_word; pa.Wf[4] = Wk_word; pa.Xh[4] = Xw_h; pa.Xl[4] = Xw_l;
  pa.Wh[4] = Wkw_h; pa.Wl[4] = Wkw_l;
  pa.bias[4] = bk_word; pa.scale[4] = 1.0f;   pa.dh[4] = kwT_h; pa.dl[4] = kwT_l; pa.T[4] = 512; pa.md[4] = 2;
  proj_all_kernel<<<dim3(8, 32, 5), 256, 0, stream>>>(pa);

  msplit_kernel<<<dim3(4 * 1024 * 512 / 256), 256, 0, stream>>>(mapping, M_h, M_l, M_f);

  rel_bpe_kernel<<<dim3(64 * 1024 / 256), 256, 0, stream>>>(q_bpe, relk, R_bpe);
  rel_word_kernel<<<dim3(64 * 512 / 256), 256, 0, stream>>>(qwT_h, qwT_l, relk, R_word);

  for (int n0 = 0; n0 < 64; n0 += NC) {
    relprefix_kernel<<<dim3(NC * 20), 256, 0, stream>>>(R_word, M_f, RelT, PS, NC, n0);
    mqk_kernel<<<dim3(8, NC), 256, 0, stream>>>(M_h, M_l, qwT_h, qwT_l, kwT_h, kwT_l,
                                                MQh, MQl, MKh, MKl, n0);
    stage1band_kernel<<<dim3(16, 8, NC), 256, 0, stream>>>(M_f, RelT, PS, C1r, n0);
    logits_kernel<<<dim3(8, 8, NC), 256, 0, stream>>>(q_bpe, k_bpe, MQh, MQl, MKh, MKl,
                                                      C1r, M_f, R_bpe, L_c, n0);
    softmax_pv_kernel<<<dim3(16, NC), 256, 0, stream>>>(L_c, VTb, AO, n0);
  }

  outproj_kernel<<<dim3(8, 32), 256, 0, stream>>>(AO, Wo, Wo_bf, prep, bo, (float*)d_out);
}

// Round 6
// 596.842 us; speedup vs baseline: 1.2860x; 1.0508x over previous
//
#include <hip/hip_runtime.h>

// RelativeBPEWORDFusionMultiheadAttention on MI355X (gfx950). FP32 in/out.
// Factorization: fused = (MQ)(MK)^T + M·Rel·M^T (content Dekker-bf16, Rel fp16).
// Round 13c (fix compile: no LDS pointer arrays — gfx950 rejects static
// addrspacecast initializers; use runtime POOL+i*4096 arithmetic instead).
// (a) proj split into md01 (33KB LDS, 4 blk/CU) + md2 (64KB), both with
// bijective XCD swizzle so blocks sharing an A-panel land on one XCD L2.
// (b) md0 epilogue transposes via LDS -> 128B stores. (c) softmax_pv:
// counted-vmcnt pipeline + qt->XCD swizzle. (d) stage1band grid swap.

#define DEV __device__ __forceinline__
#define GAS(x) ((const __attribute__((address_space(1))) unsigned*)(x))
#define LAS(x) ((__attribute__((address_space(3))) unsigned*)(x))

typedef unsigned short u16;
typedef __attribute__((ext_vector_type(8))) short short8;
typedef __attribute__((ext_vector_type(8))) _Float16 half8;
typedef __attribute__((ext_vector_type(4))) float floatx4;

DEV float bf2f(u16 u) { union { unsigned u; float f; } v; v.u = ((unsigned)u) << 16; return v.f; }
DEV u16 f2bf(float f) {
  union { float f; unsigned u; } v; v.f = f;
  unsigned r = v.u + 0x7FFFu + ((v.u >> 16) & 1u);  // RNE
  return (u16)(r >> 16);
}
DEV u16 f2h_bits(float f) { union { _Float16 h; u16 u; } v; v.h = (_Float16)f; return v.u; }

// counted wait: only the N oldest vector-memory ops may remain outstanding
template <int N> DEV void vmwait() {
  asm volatile("s_waitcnt vmcnt(%0)" ::"n"(N) : "memory");
  __builtin_amdgcn_sched_barrier(0);
}
DEV void barrier_raw() {
  asm volatile("" ::: "memory");
  __builtin_amdgcn_s_barrier();
  asm volatile("" ::: "memory");
}

// ---- LDS tile [128][32] u16, 16B-chunk XOR swizzle (source-side permute) ----
DEV void stage_u16(const u16* g, int ld, u16* lds, int tid) {
#pragma unroll
  for (int p = 0; p < 2; ++p) {
    int o = (p * 256 + tid) * 16;
    int r = o >> 6, c = (o >> 4) & 3, sc = c ^ ((r >> 1) & 3);
    __builtin_amdgcn_global_load_lds(GAS(g + (size_t)r * ld + sc * 8),
                                     LAS((char*)lds + o), 16, 0, 0);
  }
}

DEV void stage_u16_half(const u16* g, int ld, u16* lds, int tid, int p) {
  int o = (p * 256 + tid) * 16;
  int r = o >> 6, c = (o >> 4) & 3, sc = c ^ ((r >> 1) & 3);
  __builtin_amdgcn_global_load_lds(GAS(g + (size_t)(r - p * 64) * ld + sc * 8),
                                   LAS((char*)lds + o), 16, 0, 0);
}

DEV void stage_f32_bf(const float* g, int ld, u16* lds, int tid) {
#pragma unroll
  for (int p = 0; p < 2; ++p) {
    int o = (p * 256 + tid) * 16;
    int r = o >> 6, c = (o >> 4) & 3, sc = c ^ ((r >> 1) & 3);
    const float* src = g + (size_t)r * ld + sc * 8;
    union { short8 s; u16 u[8]; } oh;
#pragma unroll
    for (int j = 0; j < 8; ++j) oh.u[j] = f2bf(src[j]);
    *(short8*)((char*)lds + o) = oh.s;
  }
}

DEV void stage_f32_split(const float* g, int ld, u16* ldsh, u16* ldsl, int tid) {
#pragma unroll
  for (int p = 0; p < 2; ++p) {
    int o = (p * 256 + tid) * 16;
    int r = o >> 6, c = (o >> 4) & 3, sc = c ^ ((r >> 1) & 3);
    const float* src = g + (size_t)r * ld + sc * 8;
    union { short8 s; u16 u[8]; } oh, ol;
#pragma unroll
    for (int j = 0; j < 8; ++j) {
      float f = src[j];
      u16 h = f2bf(f);
      oh.u[j] = h;
      ol.u[j] = f2bf(f - bf2f(h));
    }
    *(short8*)((char*)ldsh + o) = oh.s;
    *(short8*)((char*)ldsl + o) = ol.s;
  }
}

DEV short8 frag_ld(const u16* lds, int row, int quad) {
  int c = quad ^ ((row >> 1) & 3);
  return *(const short8*)(lds + row * 32 + c * 8);
}

DEV void mma_bf16(const u16* As, const u16* Bs, int wr, int wc, int m, int quad, floatx4 acc[4][4]) {
  short8 af[4], bf[4];
#pragma unroll
  for (int t = 0; t < 4; ++t) af[t] = frag_ld(As, wr * 64 + t * 16 + m, quad);
#pragma unroll
  for (int t = 0; t < 4; ++t) bf[t] = frag_ld(Bs, wc * 64 + t * 16 + m, quad);
#pragma unroll
  for (int rt = 0; rt < 4; ++rt)
#pragma unroll
    for (int ct = 0; ct < 4; ++ct)
      acc[rt][ct] = __builtin_amdgcn_mfma_f32_16x16x32_bf16(af[rt], bf[ct], acc[rt][ct], 0, 0, 0);
}

DEV void mma_f16(const u16* As, const u16* Bs, int wr, int wc, int m, int quad, floatx4 acc[4][4]) {
  union { short8 s; half8 h; } af[4], bf[4];
#pragma unroll
  for (int t = 0; t < 4; ++t) af[t].s = frag_ld(As, wr * 64 + t * 16 + m, quad);
#pragma unroll
  for (int t = 0; t < 4; ++t) bf[t].s = frag_ld(Bs, wc * 64 + t * 16 + m, quad);
#pragma unroll
  for (int rt = 0; rt < 4; ++rt)
#pragma unroll
    for (int ct = 0; ct < 4; ++ct)
      acc[rt][ct] = __builtin_amdgcn_mfma_f32_16x16x32_f16(af[rt].h, bf[ct].h, acc[rt][ct], 0, 0, 0);
}

// Dekker 3-pass: hh + hl + lh (bf16 operands, ~2^-16 effective)
DEV void mma_split(const u16* AsH, const u16* AsL, const u16* BsH, const u16* BsL,
                   int wr, int wc, int m, int quad, floatx4 acc[4][4]) {
  short8 ah[4], al[4], bh[4], bl[4];
#pragma unroll
  for (int t = 0; t < 4; ++t) {
    ah[t] = frag_ld(AsH, wr * 64 + t * 16 + m, quad);
    al[t] = frag_ld(AsL, wr * 64 + t * 16 + m, quad);
    bh[t] = frag_ld(BsH, wc * 64 + t * 16 + m, quad);
    bl[t] = frag_ld(BsL, wc * 64 + t * 16 + m, quad);
  }
#pragma unroll
  for (int rt = 0; rt < 4; ++rt)
#pragma unroll
    for (int ct = 0; ct < 4; ++ct) {
      acc[rt][ct] = __builtin_amdgcn_mfma_f32_16x16x32_bf16(ah[rt], bh[ct], acc[rt][ct], 0, 0, 0);
      acc[rt][ct] = __builtin_amdgcn_mfma_f32_16x16x32_bf16(ah[rt], bl[ct], acc[rt][ct], 0, 0, 0);
      acc[rt][ct] = __builtin_amdgcn_mfma_f32_16x16x32_bf16(al[rt], bh[ct], acc[rt][ct], 0, 0, 0);
    }
}

DEV void acc_zero(floatx4 acc[4][4]) {
  floatx4 z = {0.f, 0.f, 0.f, 0.f};
#pragma unroll
  for (int i = 0; i < 4; ++i)
#pragma unroll
    for (int j = 0; j < 4; ++j) acc[i][j] = z;
}

// ---------------- input pre-conversion ----------------
struct CvtB { const float* src[5]; u16* dst[5]; int n8[5]; };
__global__ __launch_bounds__(256) void cvt_bf_kernel(CvtB a) {
  int z = blockIdx.z;
  int i = blockIdx.x * 256 + threadIdx.x;
  if (i >= a.n8[z]) return;
  const float* s = a.src[z] + (size_t)i * 8;
  union { short8 v; u16 u[8]; } o;
#pragma unroll
  for (int j = 0; j < 8; ++j) o.u[j] = f2bf(s[j]);
  *(short8*)(a.dst[z] + (size_t)i * 8) = o.v;
}

struct CvtS { const float* src[3]; u16* dh[3]; u16* dl[3]; int n8[3]; };
__global__ __launch_bounds__(256) void cvt_split_kernel(CvtS a) {
  int z = blockIdx.z;
  int i = blockIdx.x * 256 + threadIdx.x;
  if (i >= a.n8[z]) return;
  const float* s = a.src[z] + (size_t)i * 8;
  union { short8 v; u16 u[8]; } oh, ol;
#pragma unroll
  for (int j = 0; j < 8; ++j) {
    float f = s[j];
    u16 h = f2bf(f);
    oh.u[j] = h;
    ol.u[j] = f2bf(f - bf2f(h));
  }
  *(short8*)(a.dh[z] + (size_t)i * 8) = oh.v;
  *(short8*)(a.dl[z] + (size_t)i * 8) = ol.v;
}

// ---------------- projections ----------------
// z: 0=q_bpe(bf16) 1=k_bpe(bf16) 2=V->VT(bf16) 3=q_word(Dekker) 4=k_word(Dekker)
struct PAll {
  const float* Xf[5]; const float* Wf[5];
  const u16* Xh[5]; const u16* Xl[5]; const u16* Wh[5]; const u16* Wl[5];
  const float* bias[5]; float scale[5];
  u16* dh[5]; u16* dl[5]; int T[5]; int md[5]; int prep;
};

// md 0/1 (bf16, T=1024): 33 KB LDS -> 4 blocks/CU. XCD swizzle: by -> p%8.
__global__ __launch_bounds__(256) void proj_md01_kernel(PAll a) {
  const int z = blockIdx.z;            // 0..2
  __shared__ __align__(16) u16 POOL[16640];  // 33280 B: K-loop 4x4096 + transpose 128x130
  auto LB = [&](int i) -> u16* { return POOL + i * 4096; };
  const int tid = threadIdx.x;
  const int lane = tid & 63, wv = tid >> 6, wr = wv >> 1, wc = wv & 1;
  const int m = lane & 15, quad = lane >> 4;
  const int md = a.md[z], prep = a.prep;
  const int p = blockIdx.x + 8 * blockIdx.y;
  const int bx = (p >> 3) & 7, by = (p & 7) + 8 * (p >> 6);
  const size_t arow = (size_t)by * 128 * 1024;
  const size_t brow = (size_t)bx * 128 * 1024;
  floatx4 acc[4][4];
  acc_zero(acc);
  if (prep) {
    const u16* Xh = a.Xh[z]; const u16* Wh = a.Wh[z];
    stage_u16(Xh + arow, 1024, LB(0), tid);
    stage_u16(Wh + brow, 1024, LB(1), tid);
    for (int k0 = 0; k0 < 1024; k0 += 32) {
      int o = ((k0 >> 5) & 1) * 2;
      if (k0 + 32 < 1024) {
        int no = 2 - o;
        stage_u16(Xh + arow + k0 + 32, 1024, LB(no), tid);
        stage_u16(Wh + brow + k0 + 32, 1024, LB(no + 1), tid);
        vmwait<4>();
      } else vmwait<0>();
      barrier_raw();
      mma_bf16(LB(o), LB(o + 1), wr, wc, m, quad, acc);
      barrier_raw();
    }
  } else {
    for (int k0 = 0; k0 < 1024; k0 += 32) {
      __syncthreads();
      stage_f32_bf(a.Xf[z] + arow + k0, 1024, LB(0), tid);
      stage_f32_bf(a.Wf[z] + brow + k0, 1024, LB(2), tid);
      __syncthreads();
      mma_bf16(LB(0), LB(2), wr, wc, m, quad, acc);
    }
    __syncthreads();
  }
  const float scale = a.scale[z];
  const float* bias = a.bias[z];
  u16* dh = a.dh[z];
  const int row0l = wr * 64 + quad * 4;
  const int col0l = wc * 64 + m;
  // both md0 and md1: transpose via LDS, 128B-contiguous stores
  u16* TB = POOL;  // [128 cols][130]
  __syncthreads();
#pragma unroll
  for (int rt = 0; rt < 4; ++rt)
#pragma unroll
    for (int ct = 0; ct < 4; ++ct) {
      int cl = col0l + ct * 16;
      float bi = bias[bx * 128 + cl];
#pragma unroll
      for (int rg = 0; rg < 4; ++rg) {
        int rl = row0l + rt * 16 + rg;
        TB[(size_t)cl * 130 + rl] = f2bf((acc[rt][ct][rg] + bi) * scale);
      }
    }
  __syncthreads();
  if (md == 0) {
    // dst [n][t][64]: task per (n_local 0..7, t_local 0..31)
    int t_local = tid & 31, nloc = tid >> 5;
    int bb = nloc >> 1, hl = nloc & 1;
    int n = bb * 16 + bx * 2 + hl;
    int rl = t_local * 4 + bb;
    size_t base = ((size_t)n * 1024 + by * 32 + t_local) * 64;
#pragma unroll
    for (int g = 0; g < 8; ++g) {
      union { short8 v; u16 u[8]; } o;
#pragma unroll
      for (int j = 0; j < 8; ++j) o.u[j] = TB[(size_t)(hl * 64 + g * 8 + j) * 130 + rl];
      *(short8*)(dh + base + g * 8) = o.v;
    }
  } else {
    // dst VT[n][d][t]: runs of 32 t per (col, bb)
    for (int task = tid; task < 512; task += 256) {
      int c = task & 127, bb = task >> 7;
      int colg = bx * 128 + c, h = colg >> 6, d = colg & 63;
      size_t base = (((size_t)(bb * 16 + h)) * 64 + d) * 1024 + (size_t)by * 32;
#pragma unroll
      for (int g = 0; g < 4; ++g) {
        union { short8 v; u16 u[8]; } o;
#pragma unroll
        for (int j = 0; j < 8; ++j) o.u[j] = TB[(size_t)c * 130 + bb + 4 * (g * 8 + j)];
        *(short8*)(dh + base + g * 8) = o.v;
      }
    }
  }
}

// md 2 (Dekker h/l, T=512): 64 KB LDS. XCD swizzle.
__global__ __launch_bounds__(256) void proj_md2_kernel(PAll a) {
  const int z = blockIdx.z + 3;        // 3,4
  __shared__ __align__(16) u16 POOL[32768];  // 64 KB
  auto LB = [&](int i) -> u16* { return POOL + i * 4096; };
  const int tid = threadIdx.x;
  const int lane = tid & 63, wv = tid >> 6, wr = wv >> 1, wc = wv & 1;
  const int m = lane & 15, quad = lane >> 4;
  const int prep = a.prep;
  const int p = blockIdx.x + 8 * blockIdx.y;            // 0..127
  const int bx = (p >> 3) & 7, by = (p & 7) + 8 * (p >> 6);
  const size_t arow = (size_t)by * 128 * 1024;
  const size_t brow = (size_t)bx * 128 * 1024;
  floatx4 acc[4][4];
  acc_zero(acc);
  if (prep) {
    const u16* Xh = a.Xh[z]; const u16* Xl = a.Xl[z];
    const u16* Wh = a.Wh[z]; const u16* Wl = a.Wl[z];
    stage_u16(Xh + arow, 1024, LB(0), tid);
    stage_u16(Wh + brow, 1024, LB(1), tid);
    stage_u16(Xl + arow, 1024, LB(2), tid);
    stage_u16(Wl + brow, 1024, LB(3), tid);
    for (int k0 = 0; k0 < 1024; k0 += 32) {
      int o = ((k0 >> 5) & 1) * 4;
      if (k0 + 32 < 1024) {
        int no = 4 - o;
        stage_u16(Xh + arow + k0 + 32, 1024, LB(no), tid);
        stage_u16(Wh + brow + k0 + 32, 1024, LB(no + 1), tid);
        stage_u16(Xl + arow + k0 + 32, 1024, LB(no + 2), tid);
        stage_u16(Wl + brow + k0 + 32, 1024, LB(no + 3), tid);
        vmwait<8>();
      } else vmwait<0>();
      barrier_raw();
      mma_split(LB(o), LB(o + 2), LB(o + 1), LB(o + 3), wr, wc, m, quad, acc);
      barrier_raw();
    }
  } else {
    for (int k0 = 0; k0 < 1024; k0 += 32) {
      __syncthreads();
      stage_f32_split(a.Xf[z] + arow + k0, 1024, LB(0), LB(4), tid);
      stage_f32_split(a.Wf[z] + brow + k0, 1024, LB(2), LB(6), tid);
      __syncthreads();
      mma_split(LB(0), LB(4), LB(2), LB(6), wr, wc, m, quad, acc);
    }
    __syncthreads();
  }
  const float scale = a.scale[z];
  const float* bias = a.bias[z];
  u16* dh = a.dh[z];
  u16* dl = a.dl[z];
  const int row0l = wr * 64 + quad * 4;
  // Dekker h/l transposed stores, two col-half passes
  u16* TBh = POOL;              // [64][130]
  u16* TBl = POOL + 64 * 130;
  for (int pass = 0; pass < 2; ++pass) {
    __syncthreads();
    if (wc == pass) {
#pragma unroll
      for (int rt = 0; rt < 4; ++rt)
#pragma unroll
        for (int ct = 0; ct < 4; ++ct) {
          int cl = ct * 16 + m;
          float bi = bias[bx * 128 + pass * 64 + cl];
#pragma unroll
          for (int rg = 0; rg < 4; ++rg) {
            int rl = row0l + rt * 16 + rg;
            float val = (acc[rt][ct][rg] + bi) * scale;
            u16 hh = f2bf(val);
            TBh[(size_t)cl * 130 + rl] = hh;
            TBl[(size_t)cl * 130 + rl] = f2bf(val - bf2f(hh));
          }
        }
    }
    __syncthreads();
    int c2 = tid & 63, bb = tid >> 6;
    int colg = bx * 128 + pass * 64 + c2, h = colg >> 6, d = colg & 63;
    size_t base = (((size_t)(bb * 16 + h)) * 64 + d) * 512 + (size_t)by * 32;
#pragma unroll
    for (int g = 0; g < 4; ++g) {
      union { short8 v; u16 u[8]; } oh, ol;
#pragma unroll
      for (int j = 0; j < 8; ++j) {
        oh.u[j] = TBh[(size_t)c2 * 130 + bb + 4 * (g * 8 + j)];
        ol.u[j] = TBl[(size_t)c2 * 130 + bb + 4 * (g * 8 + j)];
      }
      *(short8*)(dh + base + g * 8) = oh.v;
      *(short8*)(dl + base + g * 8) = ol.v;
    }
  }
}

// ---------------- M -> Mh,Ml (bf16 Dekker) + Mf (fp16) ----------------
__global__ __launch_bounds__(256) void msplit_kernel(const float* __restrict__ M,
                                                     u16* __restrict__ Mh, u16* __restrict__ Ml,
                                                     u16* __restrict__ Mf) {
  int i = blockIdx.x * 256 + threadIdx.x;
  float f = M[i];
  u16 h = f2bf(f);
  Mh[i] = h;
  Ml[i] = f2bf(f - bf2f(h));
  Mf[i] = f2h_bits(f);
}

// ---------------- rel tables ----------------
__global__ __launch_bounds__(256) void rel_bpe_kernel(const u16* __restrict__ q,
                                                      const float* __restrict__ relk,
                                                      float* __restrict__ R) {
  int nt = blockIdx.x * 256 + threadIdx.x;
  float qv[64];
#pragma unroll
  for (int c = 0; c < 8; ++c) {
    union { short8 s; u16 u[8]; } uh; uh.s = *(const short8*)(q + (size_t)nt * 64 + c * 8);
#pragma unroll
    for (int j = 0; j < 8; ++j) qv[c * 8 + j] = bf2f(uh.u[j]);
  }
  for (int r = 0; r < 33; ++r) {
    const float* krow = relk + r * 64;
    float s = 0.f;
#pragma unroll
    for (int d = 0; d < 64; ++d) s += qv[d] * krow[d];
    R[(size_t)nt * 33 + r] = s;
  }
}

__global__ __launch_bounds__(256) void rel_word_kernel(const u16* __restrict__ qh, const u16* __restrict__ ql,
                                                       const float* __restrict__ relk,
                                                       float* __restrict__ R) {
  int nt = blockIdx.x * 256 + threadIdx.x;
  int n = nt >> 9, w = nt & 511;
  float qv[64];
#pragma unroll
  for (int d = 0; d < 64; ++d) {
    size_t idx = ((size_t)n * 64 + d) * 512 + w;
    qv[d] = bf2f(qh[idx]) + bf2f(ql[idx]);
  }
  for (int r = 0; r < 33; ++r) {
    const float* krow = relk + r * 64;
    float s = 0.f;
#pragma unroll
    for (int d = 0; d < 64; ++d) s += qv[d] * krow[d];
    R[(size_t)nt * 33 + r] = s;
  }
}

// ---- merged RelT build + coarse prefixes (one launch per chunk) -------------
__global__ __launch_bounds__(256) void relprefix_kernel(const float* __restrict__ Rw,
                                                        const u16* __restrict__ Mf,
                                                        u16* __restrict__ RT,
                                                        float* __restrict__ PS,
                                                        int NCx, int n0) {
  const int bx = blockIdx.x;
  if (bx < NCx * 16) {
    int i = bx * 256 + threadIdx.x;
    int w8 = i & 7, s = (i >> 3) & 31, t = (i >> 8) & 15, nl = i >> 12;
    int n = n0 + nl;
    int w0 = (t == 0) ? 0 : (t == 15 ? 448 : 32 * t - 16);
    int sg = t * 32 + s;
    const float* R = Rw + (size_t)n * 512 * 33;
    union { short8 v; u16 u[8]; } o;
#pragma unroll
    for (int j = 0; j < 8; ++j) {
      int w = w0 + w8 * 8 + j;
      int d = sg - w; d = d < -16 ? -16 : (d > 16 ? 16 : d);
      o.u[j] = f2h_bits(R[(size_t)w * 33 + d + 16]);
    }
    *(short8*)(RT + (size_t)i * 8) = o.v;
  } else {
    const int px = bx - NCx * 16;
    const int nl = px >> 2, n = n0 + nl, b = n >> 4;
    const int q = (px & 3) * 256 + threadIdx.x;
    const u16* mrow = Mf + ((size_t)b * 1024 + q) * 512;
    const float* R = Rw + (size_t)n * 512 * 33;
    float* ps = PS + ((size_t)nl * 1024 + q) * 66;
    float blkA[32], blkB[32];
#pragma unroll
    for (int t = 0; t < 32; ++t) {
      float a = 0.f, bb = 0.f;
#pragma unroll
      for (int c = 0; c < 2; ++c) {
        union { short8 s; _Float16 h[8]; } u;
        u.s = *(const short8*)(mrow + t * 16 + c * 8);
#pragma unroll
        for (int j = 0; j < 8; ++j) {
          int w = t * 16 + c * 8 + j;
          float mv = (float)u.h[j];
          a += mv * R[(size_t)w * 33 + 32];
          bb += mv * R[(size_t)w * 33];
        }
      }
      blkA[t] = a; blkB[t] = bb;
    }
    float run = 0.f;
#pragma unroll
    for (int i = 0; i < 33; ++i) { ps[i] = run; if (i < 32) run += blkA[i]; }
    float tot = 0.f;
#pragma unroll
    for (int i = 0; i < 32; ++i) tot += blkB[i];
    run = tot;
#pragma unroll
    for (int i = 0; i < 33; ++i) { ps[33 + i] = run; if (i < 32) run -= blkB[i]; }
  }
}

// ---- stage1 band: C1r[nl][q][s] = K=64 windowed MFMA + alpha[q] + beta[q] ----
// grid (8 q-tiles, 16 t, NC): x = q-tile so the 16 t-blocks sharing a q-panel
// land on one XCD (x-fastest dispatch).
__global__ __launch_bounds__(256) void stage1band_kernel(const u16* __restrict__ Mf,
                                                         const u16* __restrict__ RT,
                                                         const float* __restrict__ PS,
                                                         u16* __restrict__ C1r, int n0) {
  __shared__ __align__(16) u16 As0[4096], As1[4096], Bs0[1024], Bs1[1024];
  const int tid = threadIdx.x, qy = blockIdx.x, t = blockIdx.y;
  const int nl = blockIdx.z, n = n0 + nl, b = n >> 4;
  const int lane = tid & 63, wv = tid >> 6;
  const int m = lane & 15, quad = lane >> 4;
  const int w0 = (t == 0) ? 0 : (t == 15 ? 448 : 32 * t - 16);
  const size_t ma = ((size_t)b * 1024 + qy * 128) * 512 + w0;
  const u16* rt = RT + ((size_t)nl * 16 + t) * 2048;
  stage_u16(Mf + ma, 512, As0, tid);
  stage_u16(Mf + ma + 32, 512, As1, tid);
  {
    int half = tid >> 7, tt = tid & 127, o = tt * 16;
    int r = o >> 6, c = (o >> 4) & 3, sc = c ^ ((r >> 1) & 3);
    u16* bs = half ? Bs1 : Bs0;
    __builtin_amdgcn_global_load_lds(GAS(rt + half * 32 + (size_t)r * 64 + sc * 8),
                                     LAS((char*)bs + o), 16, 0, 0);
  }
  floatx4 acc[2][2];
  floatx4 z = {0.f, 0.f, 0.f, 0.f};
  acc[0][0] = z; acc[0][1] = z; acc[1][0] = z; acc[1][1] = z;
  __syncthreads();
#pragma unroll
  for (int ks = 0; ks < 2; ++ks) {
    const u16* As = ks ? As1 : As0;
    const u16* Bs = ks ? Bs1 : Bs0;
    union { short8 s; half8 h; } af[2], bf[2];
#pragma unroll
    for (int i = 0; i < 2; ++i) af[i].s = frag_ld(As, wv * 32 + i * 16 + m, quad);
#pragma unroll
    for (int i = 0; i < 2; ++i) bf[i].s = frag_ld(Bs, i * 16 + m, quad);
#pragma unroll
    for (int i = 0; i < 2; ++i)
#pragma unroll
      for (int j = 0; j < 2; ++j)
        acc[i][j] = __builtin_amdgcn_mfma_f32_16x16x32_f16(af[i].h, bf[j].h, acc[i][j], 0, 0, 0);
  }
  const int ia = w0 >> 4, ib = (w0 + 64) >> 4;
  const float* ps = PS + ((size_t)nl * 1024 + qy * 128) * 66;
#pragma unroll
  for (int i = 0; i < 2; ++i)
#pragma unroll
    for (int rg = 0; rg < 4; ++rg) {
      int row = wv * 32 + i * 16 + quad * 4 + rg;
      float ab = ps[(size_t)row * 66 + ia] + ps[(size_t)row * 66 + 33 + ib];
      int q = qy * 128 + row;
#pragma unroll
      for (int j = 0; j < 2; ++j) {
        int s = t * 32 + j * 16 + m;
        C1r[((size_t)nl * 1024 + q) * 512 + s] = f2h_bits(acc[i][j][rg] + ab);
      }
    }
}

// ---------------- MQ/MK: [1024,64] = M[1024,512] x {Q,K}^T, Dekker 3-pass ------
__global__ __launch_bounds__(256) void mqk_kernel(const u16* __restrict__ Mh, const u16* __restrict__ Ml,
                                                  const u16* __restrict__ qwTh, const u16* __restrict__ qwTl,
                                                  const u16* __restrict__ kwTh, const u16* __restrict__ kwTl,
                                                  u16* __restrict__ MQh, u16* __restrict__ MQl,
                                                  u16* __restrict__ MKh, u16* __restrict__ MKl, int n0) {
  __shared__ __align__(16) u16 POOL[32768];
  auto LB = [&](int i) -> u16* { return POOL + i * 4096; };
  const int tid = threadIdx.x, nl = blockIdx.y, n = n0 + nl, b = n >> 4;
  const int lane = tid & 63, wv = tid >> 6, wr = wv >> 1, wc = wv & 1;
  const int m = lane & 15, quad = lane >> 4;
  const size_t ma = ((size_t)b * 1024 + blockIdx.x * 128) * 512;
  const u16* Qh = qwTh + (size_t)n * 32768;
  const u16* Ql = qwTl + (size_t)n * 32768;
  const u16* Kh = kwTh + (size_t)n * 32768;
  const u16* Kl = kwTl + (size_t)n * 32768;
  floatx4 acc[4][4];
  acc_zero(acc);
  auto stage_set = [&](int o, int k) {
    stage_u16(Mh + ma + k, 512, LB(o), tid);
    stage_u16(Ml + ma + k, 512, LB(o + 1), tid);
    stage_u16_half(Qh + k, 512, LB(o + 2), tid, 0);
    stage_u16_half(Kh + k, 512, LB(o + 2), tid, 1);
    stage_u16_half(Ql + k, 512, LB(o + 3), tid, 0);
    stage_u16_half(Kl + k, 512, LB(o + 3), tid, 1);
  };
  stage_set(0, 0);
  for (int k0 = 0; k0 < 512; k0 += 32) {
    int o = ((k0 >> 5) & 1) * 4;
    if (k0 + 32 < 512) {
      stage_set(4 - o, k0 + 32);
      vmwait<8>();
    } else vmwait<0>();
    barrier_raw();
    mma_split(LB(o), LB(o + 1), LB(o + 2), LB(o + 3), wr, wc, m, quad, acc);
    barrier_raw();
  }
  u16* dsth = wc ? MKh : MQh;
  u16* dstl = wc ? MKl : MQl;
  const int row0 = blockIdx.x * 128 + wr * 64 + quad * 4;
#pragma unroll
  for (int rt = 0; rt < 4; ++rt)
#pragma unroll
    for (int ct = 0; ct < 4; ++ct) {
      int d = (ct * 16 + m) & 63;
#pragma unroll
      for (int rg = 0; rg < 4; ++rg) {
        int row = row0 + rt * 16 + rg;
        size_t idx = ((size_t)nl * 1024 + row) * 64 + d;
        float val = acc[rt][ct][rg];
        u16 hh = f2bf(val);
        dsth[idx] = hh;
        dstl[idx] = f2bf(val - bf2f(hh));
      }
    }
}

// ------ logits: qb.kb (bf16,K64) + MQ.MK^T (Dekker,K64) + C1r.Mf^T (fp16,K512) + rel --
__global__ __launch_bounds__(256) void logits_kernel(const u16* __restrict__ qb, const u16* __restrict__ kb,
                                                     const u16* __restrict__ MQh, const u16* __restrict__ MQl,
                                                     const u16* __restrict__ MKh, const u16* __restrict__ MKl,
                                                     const u16* __restrict__ C1r, const u16* __restrict__ Mf,
                                                     const float* __restrict__ Rb, u16* __restrict__ L,
                                                     int n0) {
  __shared__ __align__(16) u16 POOL[16384];
  auto LB = [&](int i) -> u16* { return POOL + i * 4096; };
  const int tid = threadIdx.x, nl = blockIdx.z, n = n0 + nl, b = n >> 4;
  const int bq = blockIdx.x, bk = blockIdx.y;   // x = q for XCD L2 locality
  const int lane = tid & 63, wv = tid >> 6, wr = wv >> 1, wc = wv & 1;
  const int m = lane & 15, quad = lane >> 4;
  const size_t qa = ((size_t)n * 1024 + bq * 128) * 64;
  const size_t ka = ((size_t)n * 1024 + bk * 128) * 64;
  const size_t mqa = ((size_t)nl * 1024 + bq * 128) * 64;
  const size_t mka = ((size_t)nl * 1024 + bk * 128) * 64;
  const size_t ca = ((size_t)nl * 1024 + bq * 128) * 512;
  const size_t ma = ((size_t)b * 1024 + bk * 128) * 512;
  floatx4 acc[4][4];
  acc_zero(acc);
  // loop1: content QK^T bpe (bf16, K=64)
  stage_u16(qb + qa, 64, LB(0), tid);
  stage_u16(kb + ka, 64, LB(1), tid);
  __syncthreads();
  stage_u16(qb + qa + 32, 64, LB(2), tid);
  stage_u16(kb + ka + 32, 64, LB(3), tid);
  mma_bf16(LB(0), LB(1), wr, wc, m, quad, acc);
  __syncthreads();
  mma_bf16(LB(2), LB(3), wr, wc, m, quad, acc);
  __syncthreads();
  // loop2: (MQ)(MK)^T Dekker, K=64, two 4-tile steps
#pragma unroll
  for (int k0 = 0; k0 < 64; k0 += 32) {
    stage_u16(MQh + mqa + k0, 64, LB(0), tid);
    stage_u16(MQl + mqa + k0, 64, LB(1), tid);
    stage_u16(MKh + mka + k0, 64, LB(2), tid);
    stage_u16(MKl + mka + k0, 64, LB(3), tid);
    __syncthreads();
    mma_split(LB(0), LB(1), LB(2), LB(3), wr, wc, m, quad, acc);
    __syncthreads();
  }
  // loop3: M Rel M^T part 2: C1r @ Mf^T (fp16, K=512) — counted pipeline
  stage_u16(C1r + ca, 512, LB(0), tid);
  stage_u16(Mf + ma, 512, LB(1), tid);
  for (int k0 = 0; k0 < 512; k0 += 32) {
    int o = ((k0 >> 5) & 1) * 2;
    if (k0 + 32 < 512) {
      int no = 2 - o;
      stage_u16(C1r + ca + k0 + 32, 512, LB(no), tid);
      stage_u16(Mf + ma + k0 + 32, 512, LB(no + 1), tid);
      vmwait<4>();
    } else vmwait<0>();
    barrier_raw();
    mma_f16(LB(o), LB(o + 1), wr, wc, m, quad, acc);
    barrier_raw();
  }
  const int q0 = bq * 128 + wr * 64 + quad * 4;
  const int k0c = bk * 128 + wc * 64 + m;
#pragma unroll
  for (int rt = 0; rt < 4; ++rt)
#pragma unroll
    for (int ct = 0; ct < 4; ++ct) {
      int kc = k0c + ct * 16;
#pragma unroll
      for (int rg = 0; rg < 4; ++rg) {
        int q = q0 + rt * 16 + rg;
        int id = kc - q; id = id < -16 ? -16 : (id > 16 ? 16 : id); id += 16;
        float val = acc[rt][ct][rg] + Rb[((size_t)n * 1024 + q) * 33 + id];
        L[((size_t)nl * 1024 + q) * 1024 + kc] = f2h_bits(val);
      }
    }
}

// ---------------- softmax + PV (online; fp16 logits in A-frag layout) ----------
// Counted-vmcnt V pipeline; qt->same-XCD swizzle (16 qt share one V[nl]).
__global__ __launch_bounds__(256) void softmax_pv_kernel(const u16* __restrict__ L,
                                                         const u16* __restrict__ VT,
                                                         u16* __restrict__ AO, int NCk, int n0) {
  __shared__ __align__(16) u16 Vs[2][4][2048];
  const int tid = threadIdx.x, lane = tid & 63, wv = tid >> 6;
  const int m = lane & 15, quad = lane >> 4;
  int qt, nl;
  if (NCk >= 8) {
    int lin = blockIdx.x + 16 * blockIdx.y;
    int xcd = lin & 7, j = lin >> 3;
    qt = j & 15;
    nl = xcd + 8 * (j >> 4);
  } else { qt = blockIdx.x; nl = blockIdx.y; }
  const int n = n0 + nl;
  const int qrow = qt * 64 + wv * 16 + m;
  const u16* Lrow = L + ((size_t)nl * 1024 + qrow) * 1024;
  const u16* Vbase = VT + (size_t)n * 64 * 1024;
  float mi = -1e30f, li = 0.f;
  floatx4 O[4];
  floatx4 z = {0.f, 0.f, 0.f, 0.f};
#pragma unroll
  for (int dt = 0; dt < 4; ++dt) O[dt] = z;

  auto stageV = [&](int kt, int buf) {
#pragma unroll
    for (int ct = 0; ct < 4; ++ct) {
      int o = tid * 16;
      int r = o >> 6, c = (o >> 4) & 3, sc = c ^ ((r >> 1) & 3);
      __builtin_amdgcn_global_load_lds(GAS(Vbase + (size_t)r * 1024 + kt * 128 + ct * 32 + sc * 8),
                                       LAS((char*)Vs[buf][ct] + o), 16, 0, 0);
    }
  };
  stageV(0, 0);

  for (int kt = 0; kt < 8; ++kt) {
    int cur = kt & 1;

    float vals[4][8];
#pragma unroll
    for (int ct = 0; ct < 4; ++ct) {
      union { short8 s; _Float16 h[8]; } u;
      u.s = *(const short8*)(Lrow + kt * 128 + ct * 32 + quad * 8);
#pragma unroll
      for (int j = 0; j < 8; ++j) vals[ct][j] = (float)u.h[j];
    }
    float tmax = vals[0][0];
#pragma unroll
    for (int ct = 0; ct < 4; ++ct)
#pragma unroll
      for (int j = 0; j < 8; ++j) tmax = fmaxf(tmax, vals[ct][j]);
    tmax = fmaxf(tmax, __shfl_xor(tmax, 16));
    tmax = fmaxf(tmax, __shfl_xor(tmax, 32));
    float mnew = fmaxf(mi, tmax);
    float alpha = __expf(mi - mnew);
    float pv[4][8];
    float tsum = 0.f;
#pragma unroll
    for (int ct = 0; ct < 4; ++ct)
#pragma unroll
      for (int j = 0; j < 8; ++j) { pv[ct][j] = __expf(vals[ct][j] - mnew); tsum += pv[ct][j]; }
    tsum += __shfl_xor(tsum, 16);
    tsum += __shfl_xor(tsum, 32);
    li = li * alpha + tsum;
    mi = mnew;

    if (kt + 1 < 8) { stageV(kt + 1, cur ^ 1); vmwait<4>(); }
    else vmwait<0>();
    barrier_raw();

    float ar[4];
#pragma unroll
    for (int rg = 0; rg < 4; ++rg) ar[rg] = __shfl(alpha, quad * 4 + rg);
#pragma unroll
    for (int dt = 0; dt < 4; ++dt)
#pragma unroll
      for (int rg = 0; rg < 4; ++rg) O[dt][rg] *= ar[rg];

    short8 pf[4];
#pragma unroll
    for (int ct = 0; ct < 4; ++ct) {
      union { short8 s; u16 us[8]; } up;
#pragma unroll
      for (int j = 0; j < 8; ++j) up.us[j] = f2bf(pv[ct][j]);
      pf[ct] = up.s;
    }
#pragma unroll
    for (int ct = 0; ct < 4; ++ct)
#pragma unroll
      for (int dt = 0; dt < 4; ++dt) {
        short8 vf = frag_ld(Vs[cur][ct], dt * 16 + m, quad);
        O[dt] = __builtin_amdgcn_mfma_f32_16x16x32_bf16(pf[ct], vf, O[dt], 0, 0, 0);
      }
    barrier_raw();
  }

  float linv = 1.f / li;
  float lr[4];
#pragma unroll
  for (int rg = 0; rg < 4; ++rg) lr[rg] = __shfl(linv, quad * 4 + rg);
  const int b = n >> 4, h = n & 15;
#pragma unroll
  for (int dt = 0; dt < 4; ++dt)
#pragma unroll
    for (int rg = 0; rg < 4; ++rg) {
      int q = qt * 64 + wv * 16 + quad * 4 + rg;
      float ov = O[dt][rg] * lr[rg];
      AO[((size_t)q * 4 + b) * 1024 + h * 64 + dt * 16 + m] = f2bf(ov);
    }
}

// ---------------- output projection: out = AO @ Wo^T + bo  (fp32 out) ----------
__global__ __launch_bounds__(256) void outproj_kernel(const u16* __restrict__ AO, const float* __restrict__ Wo,
                                                      const u16* __restrict__ Wob, int prep,
                                                      const float* __restrict__ bo, float* __restrict__ out) {
  __shared__ __align__(16) u16 POOL[16384];
  auto LB = [&](int i) -> u16* { return POOL + i * 4096; };
  const int tid = threadIdx.x;
  const int lane = tid & 63, wv = tid >> 6, wr = wv >> 1, wc = wv & 1;
  const int m = lane & 15, quad = lane >> 4;
  const int p = blockIdx.x + 8 * blockIdx.y;
  const int bx = (p >> 3) & 7, by = (p & 7) + 8 * (p >> 6);
  const u16* A = AO + (size_t)by * 128 * 1024;
  const size_t brow = (size_t)bx * 128 * 1024;
  floatx4 acc[4][4];
  acc_zero(acc);
  if (prep) {
    stage_u16(A, 1024, LB(0), tid);
    stage_u16(Wob + brow, 1024, LB(1), tid);
    for (int k0 = 0; k0 < 1024; k0 += 32) {
      int o = ((k0 >> 5) & 1) * 2;
      if (k0 + 32 < 1024) {
        int no = 2 - o;
        stage_u16(A + k0 + 32, 1024, LB(no), tid);
        stage_u16(Wob + brow + k0 + 32, 1024, LB(no + 1), tid);
        vmwait<4>();
      } else vmwait<0>();
      barrier_raw();
      mma_bf16(LB(o), LB(o + 1), wr, wc, m, quad, acc);
      barrier_raw();
    }
  } else {
    for (int k0 = 0; k0 < 1024; k0 += 32) {
      __syncthreads();
      stage_u16(A + k0, 1024, LB(0), tid);
      stage_f32_bf(Wo + brow + k0, 1024, LB(2), tid);
      __syncthreads();
      mma_bf16(LB(0), LB(2), wr, wc, m, quad, acc);
    }
  }
  const int r0 = by * 128 + wr * 64 + quad * 4;
  const int c0 = bx * 128 + wc * 64 + m;
#pragma unroll
  for (int rt = 0; rt < 4; ++rt)
#pragma unroll
    for (int ct = 0; ct < 4; ++ct) {
      int col = c0 + ct * 16;
      float bi = bo[col];
#pragma unroll
      for (int rg = 0; rg < 4; ++rg) {
        int row = r0 + rt * 16 + rg;
        out[(size_t)row * 1024 + col] = acc[rt][ct][rg] + bi;
      }
    }
}

extern "C" void kernel_launch(void* const* d_in, const int* in_sizes, int n_in,
                              void* d_out, int out_size, void* d_ws, size_t ws_size,
                              hipStream_t stream) {
  const float* query_bpe = (const float*)d_in[0];
  const float* query_word = (const float*)d_in[1];
  const float* mapping = (const float*)d_in[2];
  const float* Wq_bpe = (const float*)d_in[3];
  const float* bq_bpe = (const float*)d_in[4];
  const float* Wk_bpe = (const float*)d_in[5];
  const float* bk_bpe = (const float*)d_in[6];
  const float* Wq_word = (const float*)d_in[7];
  const float* bq_word = (const float*)d_in[8];
  const float* Wk_word = (const float*)d_in[9];
  const float* bk_word = (const float*)d_in[10];
  const float* Wv = (const float*)d_in[11];
  const float* bv = (const float*)d_in[12];
  const float* Wo = (const float*)d_in[13];
  const float* bo = (const float*)d_in[14];
  const float* relk = (const float*)d_in[15];

  char* ws = (char*)d_ws;
  size_t off = 0;
  u16* q_bpe = (u16*)(ws + off); off += 8388608;   // [64][1024][64] bf16
  u16* k_bpe = (u16*)(ws + off); off += 8388608;
  u16* VTb   = (u16*)(ws + off); off += 8388608;   // [64][64][1024] bf16
  u16* qwT_h = (u16*)(ws + off); off += 4194304;   // [64][64][512] bf16 hi (transposed)
  u16* qwT_l = (u16*)(ws + off); off += 4194304;
  u16* kwT_h = (u16*)(ws + off); off += 4194304;
  u16* kwT_l = (u16*)(ws + off); off += 4194304;
  u16* M_h   = (u16*)(ws + off); off += 4194304;   // [4][1024][512] bf16
  u16* M_l   = (u16*)(ws + off); off += 4194304;
  u16* M_f   = (u16*)(ws + off); off += 4194304;   // fp16
  float* R_word = (float*)(ws + off); off += 4325376;  // [64][512][33]
  float* R_bpe  = (float*)(ws + off); off += 8650752;  // [64][1024][33]
  u16* AO    = (u16*)(ws + off); off += 8388608;   // [4096][1024] bf16
  u16* Wo_bf = (u16*)(ws + off); off += 2097152;   // Wo bf16 (read at the very end)
  const size_t fixed_end = off;                    // ~79.6 MB

  // Union region: transient prep buffers (30 MB, dead after proj) overlap
  // the per-chunk loop buffers. Stream serialization makes this safe.
  const size_t avail = (ws_size > fixed_end) ? ws_size - fixed_end : 0;
  const int prep = avail >= 31457280 ? 1 : 0;
  // per-nl: RelT 64K + PS 264K + C1r 1M + L 2M + MQ/MK h+l 4x128K
  const size_t per_nc = 4005888;
  int NC = 1;
  for (int c = 64; c >= 1; c >>= 1) {
    if ((size_t)c * per_nc <= avail) { NC = c; break; }
  }
  char* vb = ws + fixed_end;
  // loop buffers
  u16* RelT  = (u16*)(vb);                                  // NC*65536
  float* PS  = (float*)(vb + (size_t)NC * 65536);           // NC*270336
  u16* C1r   = (u16*)(vb + (size_t)NC * 335872);            // NC*1048576
  u16* L_c   = (u16*)(vb + (size_t)NC * 1384448);           // NC*2097152
  u16* MQh   = (u16*)(vb + (size_t)NC * 3481600);           // NC*131072
  u16* MQl   = (u16*)(vb + (size_t)NC * 3612672);
  u16* MKh   = (u16*)(vb + (size_t)NC * 3743744);
  u16* MKl   = (u16*)(vb + (size_t)NC * 3874816);           // end NC*4005888
  // prep buffers (same bytes, earlier in time)
  u16* Xb    = (u16*)(vb);               // 8 MB  query_bpe bf16
  u16* Wqb   = (u16*)(vb + 8388608);     // 2 MB
  u16* Wkb   = (u16*)(vb + 10485760);
  u16* Wvb   = (u16*)(vb + 12582912);
  u16* Xw_h  = (u16*)(vb + 14680064);    // 4 MB
  u16* Xw_l  = (u16*)(vb + 18874368);
  u16* Wqw_h = (u16*)(vb + 23068672);    // 2 MB
  u16* Wqw_l = (u16*)(vb + 25165824);
  u16* Wkw_h = (u16*)(vb + 27262976);
  u16* Wkw_l = (u16*)(vb + 29360128);    // end 30 MB

  if (prep) {
    CvtB cb = {};
    cb.src[0] = query_bpe; cb.dst[0] = Xb;    cb.n8[0] = 524288;
    cb.src[1] = Wq_bpe;    cb.dst[1] = Wqb;   cb.n8[1] = 131072;
    cb.src[2] = Wk_bpe;    cb.dst[2] = Wkb;   cb.n8[2] = 131072;
    cb.src[3] = Wv;        cb.dst[3] = Wvb;   cb.n8[3] = 131072;
    cb.src[4] = Wo;        cb.dst[4] = Wo_bf; cb.n8[4] = 131072;
    cvt_bf_kernel<<<dim3(2048, 1, 5), 256, 0, stream>>>(cb);
    CvtS cs = {};
    cs.src[0] = query_word; cs.dh[0] = Xw_h;  cs.dl[0] = Xw_l;  cs.n8[0] = 262144;
    cs.src[1] = Wq_word;    cs.dh[1] = Wqw_h; cs.dl[1] = Wqw_l; cs.n8[1] = 131072;
    cs.src[2] = Wk_word;    cs.dh[2] = Wkw_h; cs.dl[2] = Wkw_l; cs.n8[2] = 131072;
    cvt_split_kernel<<<dim3(1024, 1, 3), 256, 0, stream>>>(cs);
  }

  PAll pa = {};
  pa.prep = prep;
  pa.Xf[0] = query_bpe;  pa.Wf[0] = Wq_bpe;  pa.Xh[0] = Xb;   pa.Wh[0] = Wqb;
  pa.bias[0] = bq_bpe;  pa.scale[0] = 0.125f; pa.dh[0] = q_bpe; pa.T[0] = 1024; pa.md[0] = 0;
  pa.Xf[1] = query_bpe;  pa.Wf[1] = Wk_bpe;  pa.Xh[1] = Xb;   pa.Wh[1] = Wkb;
  pa.bias[1] = bk_bpe;  pa.scale[1] = 1.0f;   pa.dh[1] = k_bpe; pa.T[1] = 1024; pa.md[1] = 0;
  pa.Xf[2] = query_bpe;  pa.Wf[2] = Wv;      pa.Xh[2] = Xb;   pa.Wh[2] = Wvb;
  pa.bias[2] = bv;      pa.scale[2] = 1.0f;   pa.dh[2] = VTb;   pa.T[2] = 1024; pa.md[2] = 1;
  pa.Xf[3] = query_word; pa.Wf[3] = Wq_word; pa.Xh[3] = Xw_h; pa.Xl[3] = Xw_l;
  pa.Wh[3] = Wqw_h; pa.Wl[3] = Wqw_l;
  pa.bias[3] = bq_word; pa.scale[3] = 0.125f; pa.dh[3] = qwT_h; pa.dl[3] = qwT_l; pa.T[3] = 512; pa.md[3] = 2;
  pa.Xf[4] = query_word; pa.Wf[4] = Wk_word; pa.Xh[4] = Xw_h; pa.Xl[4] = Xw_l;
  pa.Wh[4] = Wkw_h; pa.Wl[4] = Wkw_l;
  pa.bias[4] = bk_word; pa.scale[4] = 1.0f;   pa.dh[4] = kwT_h; pa.dl[4] = kwT_l; pa.T[4] = 512; pa.md[4] = 2;
  proj_md01_kernel<<<dim3(8, 32, 3), 256, 0, stream>>>(pa);
  proj_md2_kernel<<<dim3(8, 16, 2), 256, 0, stream>>>(pa);

  msplit_kernel<<<dim3(4 * 1024 * 512 / 256), 256, 0, stream>>>(mapping, M_h, M_l, M_f);

  rel_bpe_kernel<<<dim3(64 * 1024 / 256), 256, 0, stream>>>(q_bpe, relk, R_bpe);
  rel_word_kernel<<<dim3(64 * 512 / 256), 256, 0, stream>>>(qwT_h, qwT_l, relk, R_word);

  for (int n0 = 0; n0 < 64; n0 += NC) {
    relprefix_kernel<<<dim3(NC * 20), 256, 0, stream>>>(R_word, M_f, RelT, PS, NC, n0);
    mqk_kernel<<<dim3(8, NC), 256, 0, stream>>>(M_h, M_l, qwT_h, qwT_l, kwT_h, kwT_l,
                                                MQh, MQl, MKh, MKl, n0);
    stage1band_kernel<<<dim3(8, 16, NC), 256, 0, stream>>>(M_f, RelT, PS, C1r, n0);
    logits_kernel<<<dim3(8, 8, NC), 256, 0, stream>>>(q_bpe, k_bpe, MQh, MQl, MKh, MKl,
                                                      C1r, M_f, R_bpe, L_c, n0);
    softmax_pv_kernel<<<dim3(16, NC), 256, 0, stream>>>(L_c, VTb, AO, NC, n0);
  }

  outproj_kernel<<<dim3(8, 32), 256, 0, stream>>>(AO, Wo, Wo_bf, prep, bo, (float*)d_out);
}